// Round 1
// baseline (14386.905 us; speedup 1.0000x reference)
//
#include <hip/hip_runtime.h>
#include <hip/hip_bf16.h>
#include <math.h>

// Problem constants (fixed by reference: x,y are (4096, 512) fp32)
#define N 4096
#define D 512
#define EPS 0.1f
#define INV_EPS 10.0f
#define SINK_ITERS 50
#define C_CLAMP_V 1.0e6f
// log(1/4096) == -log(4096); log_mu == log_nu since n == m
#define LOG_MU (-8.317766166719343f)

typedef __bf16 bf16x8 __attribute__((ext_vector_type(8)));
typedef float floatx4 __attribute__((ext_vector_type(4)));

// ---------- convert fp32 -> bf16 ----------
__global__ void cvt_bf16_kernel(const float* __restrict__ in, __bf16* __restrict__ out, int count) {
    int idx = blockIdx.x * blockDim.x + threadIdx.x;
    if (idx < count) out[idx] = (__bf16)in[idx];
}

// ---------- row squared norms (fp32 inputs, exact) ----------
__global__ void sqnorm_kernel(const float* __restrict__ in, float* __restrict__ out) {
    int row = blockIdx.x;
    const float* p = in + (size_t)row * D;
    float s = 0.f;
    for (int k = threadIdx.x; k < D; k += 64) { float v = p[k]; s += v * v; }
    for (int off = 32; off > 0; off >>= 1) s += __shfl_down(s, off);
    if (threadIdx.x == 0) out[row] = s;
}

// ---------- C = clip(x2 + y2 - 2 * x @ y^T, 0, 1e6) via bf16 MFMA ----------
// Block = 4 waves; each wave computes a 32x32 region as 2x2 MFMA 16x16x32 tiles.
// A-frag: A[m = lane&15][k = (lane>>4)*8 + j]; B-frag identical on y rows (x@y^T).
// C/D layout: col = lane&15, row = (lane>>4)*4 + reg   [m89/m91 verified]
__global__ __launch_bounds__(256) void cost_gemm_kernel(
    const __bf16* __restrict__ xb, const __bf16* __restrict__ yb,
    const float* __restrict__ x2, const float* __restrict__ y2,
    float* __restrict__ C) {
    int w = threadIdx.x >> 6;
    int lane = threadIdx.x & 63;
    int m = lane & 15;
    int q = lane >> 4;
    int m0 = blockIdx.x * 64 + (w & 1) * 32;
    int n0 = blockIdx.y * 64 + (w >> 1) * 32;

    floatx4 acc00 = {0.f, 0.f, 0.f, 0.f};
    floatx4 acc01 = {0.f, 0.f, 0.f, 0.f};
    floatx4 acc10 = {0.f, 0.f, 0.f, 0.f};
    floatx4 acc11 = {0.f, 0.f, 0.f, 0.f};

    const bf16x8* a0p = (const bf16x8*)(xb + (size_t)(m0 + m) * D) + q;
    const bf16x8* a1p = (const bf16x8*)(xb + (size_t)(m0 + 16 + m) * D) + q;
    const bf16x8* b0p = (const bf16x8*)(yb + (size_t)(n0 + m) * D) + q;
    const bf16x8* b1p = (const bf16x8*)(yb + (size_t)(n0 + 16 + m) * D) + q;

#pragma unroll
    for (int ks = 0; ks < D / 32; ks++) {
        bf16x8 a0 = a0p[ks * 4];
        bf16x8 a1 = a1p[ks * 4];
        bf16x8 b0 = b0p[ks * 4];
        bf16x8 b1 = b1p[ks * 4];
        acc00 = __builtin_amdgcn_mfma_f32_16x16x32_bf16(a0, b0, acc00, 0, 0, 0);
        acc01 = __builtin_amdgcn_mfma_f32_16x16x32_bf16(a0, b1, acc01, 0, 0, 0);
        acc10 = __builtin_amdgcn_mfma_f32_16x16x32_bf16(a1, b0, acc10, 0, 0, 0);
        acc11 = __builtin_amdgcn_mfma_f32_16x16x32_bf16(a1, b1, acc11, 0, 0, 0);
    }

    int col = m;
#pragma unroll
    for (int r = 0; r < 4; r++) {
        int gm0 = m0 + q * 4 + r;
        int gm1 = m0 + 16 + q * 4 + r;
        float xa0 = x2[gm0], xa1 = x2[gm1];
        float yb0 = y2[n0 + col], yb1 = y2[n0 + 16 + col];
        float v;
        v = xa0 + yb0 - 2.f * acc00[r];
        C[(size_t)gm0 * N + n0 + col] = fminf(fmaxf(v, 0.f), C_CLAMP_V);
        v = xa0 + yb1 - 2.f * acc01[r];
        C[(size_t)gm0 * N + n0 + 16 + col] = fminf(fmaxf(v, 0.f), C_CLAMP_V);
        v = xa1 + yb0 - 2.f * acc10[r];
        C[(size_t)gm1 * N + n0 + col] = fminf(fmaxf(v, 0.f), C_CLAMP_V);
        v = xa1 + yb1 - 2.f * acc11[r];
        C[(size_t)gm1 * N + n0 + 16 + col] = fminf(fmaxf(v, 0.f), C_CLAMP_V);
    }
}

// ---------- f_i = -eps * (LSE_j((g_j - C_ij)/eps) + log_nu), one block per row ----------
__global__ __launch_bounds__(256) void f_update_kernel(const float* __restrict__ C,
                                                       const float* __restrict__ g,
                                                       float* __restrict__ f) {
    __shared__ float sm[256], ss[256];
    int i = blockIdx.x;
    const float* row = C + (size_t)i * N;
    float m = -INFINITY, s = 0.f;
    for (int j = threadIdx.x; j < N; j += 256) {
        float v = (g[j] - row[j]) * INV_EPS;
        if (v <= m) {
            s += __expf(v - m);
        } else {
            s = s * __expf(m - v) + 1.f;
            m = v;
        }
    }
    sm[threadIdx.x] = m; ss[threadIdx.x] = s;
    __syncthreads();
    for (int off = 128; off > 0; off >>= 1) {
        if (threadIdx.x < off) {
            float m1 = sm[threadIdx.x], s1 = ss[threadIdx.x];
            float m2 = sm[threadIdx.x + off], s2 = ss[threadIdx.x + off];
            float M = fmaxf(m1, m2);
            ss[threadIdx.x] = s1 * __expf(m1 - M) + s2 * __expf(m2 - M);
            sm[threadIdx.x] = M;
        }
        __syncthreads();
    }
    if (threadIdx.x == 0) f[i] = -EPS * (sm[0] + __logf(ss[0]) + LOG_MU);
}

// ---------- g partials: block (cb, rb) covers 256 cols x 256 rows, coalesced ----------
__global__ __launch_bounds__(256) void g_partial_kernel(const float* __restrict__ C,
                                                        const float* __restrict__ f,
                                                        float* __restrict__ pm,
                                                        float* __restrict__ ps) {
    __shared__ float sf[256];
    int cb = blockIdx.x, rb = blockIdx.y;
    int j = cb * 256 + threadIdx.x;
    sf[threadIdx.x] = f[rb * 256 + threadIdx.x];
    __syncthreads();
    float m = -INFINITY, s = 0.f;
    const float* base = C + (size_t)(rb * 256) * N + j;
#pragma unroll 4
    for (int ii = 0; ii < 256; ii++) {
        float v = (sf[ii] - base[(size_t)ii * N]) * INV_EPS;
        if (v <= m) {
            s += __expf(v - m);
        } else {
            s = s * __expf(m - v) + 1.f;
            m = v;
        }
    }
    pm[rb * N + j] = m;
    ps[rb * N + j] = s;
}

__global__ void g_combine_kernel(const float* __restrict__ pm, const float* __restrict__ ps,
                                 float* __restrict__ g) {
    int j = blockIdx.x * 256 + threadIdx.x;
    float m = -INFINITY, s = 0.f;
#pragma unroll
    for (int rb = 0; rb < 16; rb++) {
        float m2 = pm[rb * N + j], s2 = ps[rb * N + j];
        float M = fmaxf(m, m2);
        s = s * __expf(m - M) + s2 * __expf(m2 - M);
        m = M;
    }
    g[j] = -EPS * (m + __logf(s) + LOG_MU);
}

// ---------- ot = mean(f) + mean(g) ----------
__global__ void pair_reduce_kernel(const float* __restrict__ f, const float* __restrict__ g,
                                   float* __restrict__ ot_slot) {
    __shared__ float sb[256];
    float s = 0.f;
    for (int t = threadIdx.x; t < N; t += 256) s += f[t] + g[t];
    sb[threadIdx.x] = s;
    __syncthreads();
    for (int off = 128; off > 0; off >>= 1) {
        if (threadIdx.x < off) sb[threadIdx.x] += sb[threadIdx.x + off];
        __syncthreads();
    }
    if (threadIdx.x == 0) *ot_slot = sb[0] * (1.0f / 4096.0f);
}

__global__ void final_kernel(const float* __restrict__ ots, float* __restrict__ out) {
    if (threadIdx.x == 0) {
        float v = ots[0] - 0.5f * ots[1] - 0.5f * ots[2];
        out[0] = v > 0.f ? v : 0.f;
    }
}

extern "C" void kernel_launch(void* const* d_in, const int* in_sizes, int n_in,
                              void* d_out, int out_size, void* d_ws, size_t ws_size,
                              hipStream_t stream) {
    const float* x = (const float*)d_in[0];
    const float* y = (const float*)d_in[1];

    // Workspace carving (~73 MiB needed)
    char* w = (char*)d_ws;
    float* C = (float*)w;        w += (size_t)N * N * sizeof(float);      // 64 MiB
    __bf16* xb = (__bf16*)w;     w += (size_t)N * D * sizeof(__bf16);     // 4 MiB
    __bf16* yb = (__bf16*)w;     w += (size_t)N * D * sizeof(__bf16);     // 4 MiB
    float* x2 = (float*)w;       w += N * sizeof(float);
    float* y2 = (float*)w;       w += N * sizeof(float);
    float* f  = (float*)w;       w += N * sizeof(float);
    float* g  = (float*)w;       w += N * sizeof(float);
    float* pm = (float*)w;       w += 16 * N * sizeof(float);
    float* ps = (float*)w;       w += 16 * N * sizeof(float);
    float* ots = (float*)w;      w += 4 * sizeof(float);

    for (int pair = 0; pair < 3; pair++) {
        const float* a = (pair == 2) ? y : x;
        const float* b = (pair == 1) ? x : y;

        cvt_bf16_kernel<<<(N * D + 255) / 256, 256, 0, stream>>>(a, xb, N * D);
        cvt_bf16_kernel<<<(N * D + 255) / 256, 256, 0, stream>>>(b, yb, N * D);
        sqnorm_kernel<<<N, 64, 0, stream>>>(a, x2);
        sqnorm_kernel<<<N, 64, 0, stream>>>(b, y2);
        cost_gemm_kernel<<<dim3(N / 64, N / 64), 256, 0, stream>>>(xb, yb, x2, y2, C);

        hipMemsetAsync(g, 0, N * sizeof(float), stream);

        for (int it = 0; it < SINK_ITERS; it++) {
            f_update_kernel<<<N, 256, 0, stream>>>(C, g, f);
            g_partial_kernel<<<dim3(16, 16), 256, 0, stream>>>(C, f, pm, ps);
            g_combine_kernel<<<16, 256, 0, stream>>>(pm, ps, g);
        }
        pair_reduce_kernel<<<1, 256, 0, stream>>>(f, g, ots + pair);
    }
    final_kernel<<<1, 64, 0, stream>>>(ots, (float*)d_out);
}

// Round 2
// 3247.714 us; speedup vs baseline: 4.4299x; 4.4299x over previous
//
#include <hip/hip_runtime.h>
#include <hip/hip_bf16.h>
#include <math.h>

// Problem constants (fixed by reference: x,y are (4096, 512) fp32)
#define N 4096
#define D 512
#define SINK_PASSES 100           // 50 iterations x (f-update, g-update)

// log-domain constants (base-2 internally; v_exp_f32/v_log_f32 are base-2)
#define K_LOG2 14.426950408889634f          // (1/eps) * log2(e), eps = 0.1
#define TWO_K  28.853900817779268f          // 2 * K_LOG2
#define NEG_EPS_LN2 (-0.06931471805599453f) // -eps * ln(2)
#define EPS_NEG_LOGMU 0.8317766166719343f   // -eps * log_mu = eps * log(4096)

typedef __bf16   bf16x8 __attribute__((ext_vector_type(8)));
typedef _Float16 halfx8 __attribute__((ext_vector_type(8)));
typedef float    floatx4 __attribute__((ext_vector_type(4)));

// ---------- convert fp32 -> bf16 (GEMM inputs) ----------
__global__ void cvt_bf16_kernel(const float* __restrict__ in, __bf16* __restrict__ out, int count) {
    int idx = blockIdx.x * blockDim.x + threadIdx.x;
    if (idx < count) out[idx] = (__bf16)in[idx];
}

// ---------- row squared norms (fp32 inputs, exact) ----------
__global__ void sqnorm_kernel(const float* __restrict__ in, float* __restrict__ out) {
    int row = blockIdx.x;
    const float* p = in + (size_t)row * D;
    float s = 0.f;
    for (int k = threadIdx.x; k < D; k += 64) { float v = p[k]; s += v * v; }
    for (int off = 32; off > 0; off >>= 1) s += __shfl_down(s, off);
    if (threadIdx.x == 0) out[row] = s;
}

// ---------- S = a @ b^T as fp16, via bf16 MFMA ----------
// Block = 4 waves; each wave computes a 32x32 region as 2x2 MFMA 16x16x32 tiles.
// C/D layout: col = lane&15, row = (lane>>4)*4 + reg   [m89/m91 verified]
__global__ __launch_bounds__(256) void dot_gemm_kernel(
    const __bf16* __restrict__ xb, const __bf16* __restrict__ yb,
    _Float16* __restrict__ S) {
    int w = threadIdx.x >> 6;
    int lane = threadIdx.x & 63;
    int m = lane & 15;
    int q = lane >> 4;
    int m0 = blockIdx.x * 64 + (w & 1) * 32;
    int n0 = blockIdx.y * 64 + (w >> 1) * 32;

    floatx4 acc00 = {0.f, 0.f, 0.f, 0.f};
    floatx4 acc01 = {0.f, 0.f, 0.f, 0.f};
    floatx4 acc10 = {0.f, 0.f, 0.f, 0.f};
    floatx4 acc11 = {0.f, 0.f, 0.f, 0.f};

    const bf16x8* a0p = (const bf16x8*)(xb + (size_t)(m0 + m) * D) + q;
    const bf16x8* a1p = (const bf16x8*)(xb + (size_t)(m0 + 16 + m) * D) + q;
    const bf16x8* b0p = (const bf16x8*)(yb + (size_t)(n0 + m) * D) + q;
    const bf16x8* b1p = (const bf16x8*)(yb + (size_t)(n0 + 16 + m) * D) + q;

#pragma unroll
    for (int ks = 0; ks < D / 32; ks++) {
        bf16x8 a0 = a0p[ks * 4];
        bf16x8 a1 = a1p[ks * 4];
        bf16x8 b0 = b0p[ks * 4];
        bf16x8 b1 = b1p[ks * 4];
        acc00 = __builtin_amdgcn_mfma_f32_16x16x32_bf16(a0, b0, acc00, 0, 0, 0);
        acc01 = __builtin_amdgcn_mfma_f32_16x16x32_bf16(a0, b1, acc01, 0, 0, 0);
        acc10 = __builtin_amdgcn_mfma_f32_16x16x32_bf16(a1, b0, acc10, 0, 0, 0);
        acc11 = __builtin_amdgcn_mfma_f32_16x16x32_bf16(a1, b1, acc11, 0, 0, 0);
    }

    int col = m;
#pragma unroll
    for (int r = 0; r < 4; r++) {
        int gm0 = m0 + q * 4 + r;
        int gm1 = m0 + 16 + q * 4 + r;
        S[(size_t)gm0 * N + n0 + col]      = (_Float16)acc00[r];
        S[(size_t)gm0 * N + n0 + 16 + col] = (_Float16)acc01[r];
        S[(size_t)gm1 * N + n0 + col]      = (_Float16)acc10[r];
        S[(size_t)gm1 * N + n0 + 16 + col] = (_Float16)acc11[r];
    }
}

// ---------- fp16 transpose, 64x64 LDS tiles (one-time, for S_xy^T) ----------
__global__ __launch_bounds__(256) void transpose_half_kernel(const _Float16* __restrict__ in,
                                                             _Float16* __restrict__ out) {
    __shared__ _Float16 tile[64][65];
    int bi = blockIdx.x, bj = blockIdx.y;
    // load: 512 ushort8 units, 256 threads x 2
#pragma unroll
    for (int uu = 0; uu < 2; uu++) {
        int u = threadIdx.x + uu * 256;
        int r = u >> 3, c8 = u & 7;
        halfx8 v = *(const halfx8*)(in + (size_t)(bi * 64 + r) * N + bj * 64 + c8 * 8);
#pragma unroll
        for (int k = 0; k < 8; k++) tile[r][c8 * 8 + k] = v[k];
    }
    __syncthreads();
#pragma unroll
    for (int uu = 0; uu < 2; uu++) {
        int u = threadIdx.x + uu * 256;
        int rr = u >> 3, c8 = u & 7;
        halfx8 v;
#pragma unroll
        for (int k = 0; k < 8; k++) v[k] = tile[c8 * 8 + k][rr];
        *(halfx8*)(out + (size_t)(bj * 64 + rr) * N + bi * 64 + c8 * 8) = v;
    }
}

// ---------- one Sinkhorn half-iteration: row-wise log2-LSE over S ----------
// pot_out[i] = -eps*( LSE_j( (pot_in[j] - C_ij)/eps ) + log_mu ),
//   C_ij = sq_own[i] + sq_other[j] - 2*S_ij   (clamp dropped: only binds on
//   xx/yy diagonals where C = 0 +- GEMM noise; effect << tolerance)
// log2-domain: u_j = gyk[j] + TWO_K*S_ij, gyk[j] = (pot_in[j]-sq_other[j])*K;
// row shift -sq_own[i]*K applied once at the end.
__global__ __launch_bounds__(256) void lse_pass_kernel(
    const _Float16* __restrict__ S, const float* __restrict__ pot_in,
    const float* __restrict__ sq_other, const float* __restrict__ sq_own,
    float* __restrict__ pot_out) {
    __shared__ float gyk[N];
    // stage gyk into LDS (vectorized)
    {
        const floatx4* pi4 = (const floatx4*)pot_in;
        const floatx4* so4 = (const floatx4*)sq_other;
        floatx4* gy4 = (floatx4*)gyk;
        for (int t = threadIdx.x; t < N / 4; t += 256) {
            floatx4 p = pi4[t], o = so4[t];
            floatx4 r;
#pragma unroll
            for (int k = 0; k < 4; k++) r[k] = (p[k] - o[k]) * K_LOG2;
            gy4[t] = r;
        }
    }
    __syncthreads();

    int wave = threadIdx.x >> 6, lane = threadIdx.x & 63;
    int row = blockIdx.x * 4 + wave;
    float xk = sq_own[row] * K_LOG2;
    const halfx8* srow = (const halfx8*)(S + (size_t)row * N);

    float m = -INFINITY, s = 0.f;
#pragma unroll
    for (int c = 0; c < 8; c++) {
        int chunk = c * 64 + lane;   // 0..511
        halfx8 sv = srow[chunk];
        int j0 = chunk * 8;
        float u[8];
#pragma unroll
        for (int k = 0; k < 8; k++)
            u[k] = fmaf((float)sv[k], TWO_K, gyk[j0 + k]);
        float mloc = fmaxf(fmaxf(fmaxf(u[0], u[1]), fmaxf(u[2], u[3])),
                           fmaxf(fmaxf(u[4], u[5]), fmaxf(u[6], u[7])));
        float M = fmaxf(m, mloc);
        float acc = 0.f;
#pragma unroll
        for (int k = 0; k < 8; k++) acc += exp2f(u[k] - M);
        s = s * exp2f(m - M) + acc;
        m = M;
    }
    // wave-level (m,s) merge
    for (int off = 32; off > 0; off >>= 1) {
        float m2 = __shfl_down(m, off);
        float s2 = __shfl_down(s, off);
        float M = fmaxf(m, m2);
        s = s * exp2f(m - M) + s2 * exp2f(m2 - M);
        m = M;
    }
    if (lane == 0)
        pot_out[row] = NEG_EPS_LN2 * (m + __log2f(s) - xk) + EPS_NEG_LOGMU;
}

// ---------- ot = mean(f) + mean(g) ----------
__global__ void pair_reduce_kernel(const float* __restrict__ f, const float* __restrict__ g,
                                   float* __restrict__ ot_slot) {
    __shared__ float sb[256];
    float s = 0.f;
    for (int t = threadIdx.x; t < N; t += 256) s += f[t] + g[t];
    sb[threadIdx.x] = s;
    __syncthreads();
    for (int off = 128; off > 0; off >>= 1) {
        if (threadIdx.x < off) sb[threadIdx.x] += sb[threadIdx.x + off];
        __syncthreads();
    }
    if (threadIdx.x == 0) *ot_slot = sb[0] * (1.0f / 4096.0f);
}

__global__ void final_kernel(const float* __restrict__ ots, float* __restrict__ out) {
    if (threadIdx.x == 0) {
        float v = ots[0] - 0.5f * ots[1] - 0.5f * ots[2];
        out[0] = v > 0.f ? v : 0.f;
    }
}

extern "C" void kernel_launch(void* const* d_in, const int* in_sizes, int n_in,
                              void* d_out, int out_size, void* d_ws, size_t ws_size,
                              hipStream_t stream) {
    const float* x = (const float*)d_in[0];
    const float* y = (const float*)d_in[1];

    // Workspace carving (~72.1 MiB; round-1 proved >=73 MiB available)
    char* w = (char*)d_ws;
    _Float16* S  = (_Float16*)w; w += (size_t)N * N * sizeof(_Float16);   // 32 MiB
    _Float16* ST = (_Float16*)w; w += (size_t)N * N * sizeof(_Float16);   // 32 MiB
    __bf16* xb = (__bf16*)w;     w += (size_t)N * D * sizeof(__bf16);     // 4 MiB
    __bf16* yb = (__bf16*)w;     w += (size_t)N * D * sizeof(__bf16);     // 4 MiB
    float* x2 = (float*)w;       w += N * sizeof(float);
    float* y2 = (float*)w;       w += N * sizeof(float);
    float* P0 = (float*)w;       w += N * sizeof(float);
    float* P1 = (float*)w;       w += N * sizeof(float);
    float* ots = (float*)w;      w += 4 * sizeof(float);

    // One-time input prep
    cvt_bf16_kernel<<<(N * D + 255) / 256, 256, 0, stream>>>(x, xb, N * D);
    cvt_bf16_kernel<<<(N * D + 255) / 256, 256, 0, stream>>>(y, yb, N * D);
    sqnorm_kernel<<<N, 64, 0, stream>>>(x, x2);
    sqnorm_kernel<<<N, 64, 0, stream>>>(y, y2);

    for (int pair = 0; pair < 3; pair++) {
        const __bf16* a = (pair == 2) ? yb : xb;
        const __bf16* b = (pair == 1) ? xb : yb;
        const float* sqa = (pair == 2) ? y2 : x2;
        const float* sqb = (pair == 1) ? x2 : y2;

        dot_gemm_kernel<<<dim3(N / 64, N / 64), 256, 0, stream>>>(a, b, S);
        const _Float16* Srow;
        const _Float16* Scol;
        if (pair == 0) {
            transpose_half_kernel<<<dim3(N / 64, N / 64), 256, 0, stream>>>(S, ST);
            Srow = S; Scol = ST;
        } else {
            Srow = S; Scol = S;   // symmetric: col pass == row pass
        }

        hipMemsetAsync(P0, 0, N * sizeof(float), stream);  // g0 = 0

        // passes p = 1..100: odd = f-update (rows of C), even = g-update (cols)
        for (int p = 1; p <= SINK_PASSES; p++) {
            bool odd = p & 1;
            const _Float16* M = odd ? Srow : Scol;
            const float* own   = odd ? sqa : sqb;
            const float* other = odd ? sqb : sqa;
            const float* pin  = odd ? P0 : P1;
            float* pout       = odd ? P1 : P0;
            lse_pass_kernel<<<N / 4, 256, 0, stream>>>(M, pin, other, own, pout);
        }
        // f50 = P1 (pass 99), g50 = P0 (pass 100)
        pair_reduce_kernel<<<1, 256, 0, stream>>>(P1, P0, ots + pair);
    }
    final_kernel<<<1, 64, 0, stream>>>(ots, (float*)d_out);
}

// Round 3
// 2615.015 us; speedup vs baseline: 5.5017x; 1.2419x over previous
//
#include <hip/hip_runtime.h>
#include <hip/hip_bf16.h>
#include <math.h>

// Problem constants (fixed by reference: x,y are (4096, 512) fp32)
#define N 4096
#define D 512
#define SINK_PASSES 100           // 50 iterations x (f-update, g-update)

// log-domain constants (base-2 internally; v_exp_f32/v_log_f32 are base-2)
#define K_LOG2 14.426950408889634f          // (1/eps) * log2(e), eps = 0.1
#define TWO_K  28.853900817779268f          // 2 * K_LOG2
#define NEG_EPS_LN2 (-0.06931471805599453f) // -eps * ln(2)
#define EPS_NEG_LOGMU 0.8317766166719343f   // -eps * log_mu = eps * log(4096)

typedef __bf16   bf16x8 __attribute__((ext_vector_type(8)));
typedef _Float16 halfx8 __attribute__((ext_vector_type(8)));
typedef float    floatx4 __attribute__((ext_vector_type(4)));

// ---------- convert fp32 -> bf16 (GEMM inputs) ----------
__global__ void cvt_bf16_kernel(const float* __restrict__ in, __bf16* __restrict__ out, int count) {
    int idx = blockIdx.x * blockDim.x + threadIdx.x;
    if (idx < count) out[idx] = (__bf16)in[idx];
}

// ---------- row squared norms (fp32 inputs, exact) ----------
__global__ void sqnorm_kernel(const float* __restrict__ in, float* __restrict__ out) {
    int row = blockIdx.x;
    const float* p = in + (size_t)row * D;
    float s = 0.f;
    for (int k = threadIdx.x; k < D; k += 64) { float v = p[k]; s += v * v; }
    for (int off = 32; off > 0; off >>= 1) s += __shfl_down(s, off);
    if (threadIdx.x == 0) out[row] = s;
}

// ---------- S = a @ b^T as fp16, via bf16 MFMA ----------
// C/D layout: col = lane&15, row = (lane>>4)*4 + reg   [m89/m91 verified]
__global__ __launch_bounds__(256) void dot_gemm_kernel(
    const __bf16* __restrict__ xb, const __bf16* __restrict__ yb,
    _Float16* __restrict__ S) {
    int w = threadIdx.x >> 6;
    int lane = threadIdx.x & 63;
    int m = lane & 15;
    int q = lane >> 4;
    int m0 = blockIdx.x * 64 + (w & 1) * 32;
    int n0 = blockIdx.y * 64 + (w >> 1) * 32;

    floatx4 acc00 = {0.f, 0.f, 0.f, 0.f};
    floatx4 acc01 = {0.f, 0.f, 0.f, 0.f};
    floatx4 acc10 = {0.f, 0.f, 0.f, 0.f};
    floatx4 acc11 = {0.f, 0.f, 0.f, 0.f};

    const bf16x8* a0p = (const bf16x8*)(xb + (size_t)(m0 + m) * D) + q;
    const bf16x8* a1p = (const bf16x8*)(xb + (size_t)(m0 + 16 + m) * D) + q;
    const bf16x8* b0p = (const bf16x8*)(yb + (size_t)(n0 + m) * D) + q;
    const bf16x8* b1p = (const bf16x8*)(yb + (size_t)(n0 + 16 + m) * D) + q;

#pragma unroll
    for (int ks = 0; ks < D / 32; ks++) {
        bf16x8 a0 = a0p[ks * 4];
        bf16x8 a1 = a1p[ks * 4];
        bf16x8 b0 = b0p[ks * 4];
        bf16x8 b1 = b1p[ks * 4];
        acc00 = __builtin_amdgcn_mfma_f32_16x16x32_bf16(a0, b0, acc00, 0, 0, 0);
        acc01 = __builtin_amdgcn_mfma_f32_16x16x32_bf16(a0, b1, acc01, 0, 0, 0);
        acc10 = __builtin_amdgcn_mfma_f32_16x16x32_bf16(a1, b0, acc10, 0, 0, 0);
        acc11 = __builtin_amdgcn_mfma_f32_16x16x32_bf16(a1, b1, acc11, 0, 0, 0);
    }

    int col = m;
#pragma unroll
    for (int r = 0; r < 4; r++) {
        int gm0 = m0 + q * 4 + r;
        int gm1 = m0 + 16 + q * 4 + r;
        S[(size_t)gm0 * N + n0 + col]      = (_Float16)acc00[r];
        S[(size_t)gm0 * N + n0 + 16 + col] = (_Float16)acc01[r];
        S[(size_t)gm1 * N + n0 + col]      = (_Float16)acc10[r];
        S[(size_t)gm1 * N + n0 + 16 + col] = (_Float16)acc11[r];
    }
}

// ---------- fp16 transpose, 64x64 LDS tiles (one-time, for S_xy^T) ----------
__global__ __launch_bounds__(256) void transpose_half_kernel(const _Float16* __restrict__ in,
                                                             _Float16* __restrict__ out) {
    __shared__ _Float16 tile[64][65];
    int bi = blockIdx.x, bj = blockIdx.y;
#pragma unroll
    for (int uu = 0; uu < 2; uu++) {
        int u = threadIdx.x + uu * 256;
        int r = u >> 3, c8 = u & 7;
        halfx8 v = *(const halfx8*)(in + (size_t)(bi * 64 + r) * N + bj * 64 + c8 * 8);
#pragma unroll
        for (int k = 0; k < 8; k++) tile[r][c8 * 8 + k] = v[k];
    }
    __syncthreads();
#pragma unroll
    for (int uu = 0; uu < 2; uu++) {
        int u = threadIdx.x + uu * 256;
        int rr = u >> 3, c8 = u & 7;
        halfx8 v;
#pragma unroll
        for (int k = 0; k < 8; k++) v[k] = tile[c8 * 8 + k][rr];
        *(halfx8*)(out + (size_t)(bj * 64 + rr) * N + bi * 64 + c8 * 8) = v;
    }
}

// ---------- core row-LSE body, shared by both pass kernels ----------
__device__ __forceinline__ void lse_row_body(
    const _Float16* __restrict__ M, const float* __restrict__ pot_in,
    const float* __restrict__ sq_other, const float* __restrict__ sq_own,
    float* __restrict__ pot_out, float* gyk, int rowblk) {
    // stage gyk = (pot_in - sq_other) * K into LDS (vectorized)
    {
        const floatx4* pi4 = (const floatx4*)pot_in;
        const floatx4* so4 = (const floatx4*)sq_other;
        floatx4* gy4 = (floatx4*)gyk;
        for (int t = threadIdx.x; t < N / 4; t += 256) {
            floatx4 p = pi4[t], o = so4[t];
            floatx4 r;
#pragma unroll
            for (int k = 0; k < 4; k++) r[k] = (p[k] - o[k]) * K_LOG2;
            gy4[t] = r;
        }
    }
    __syncthreads();

    int wave = threadIdx.x >> 6, lane = threadIdx.x & 63;
    int row = rowblk * 4 + wave;
    float xk = sq_own[row] * K_LOG2;
    const halfx8* srow = (const halfx8*)(M + (size_t)row * N);

    float m = -INFINITY, s = 0.f;
#pragma unroll
    for (int c = 0; c < 8; c++) {
        int chunk = c * 64 + lane;   // 0..511
        halfx8 sv = srow[chunk];
        int j0 = chunk * 8;
        float u[8];
#pragma unroll
        for (int k = 0; k < 8; k++)
            u[k] = fmaf((float)sv[k], TWO_K, gyk[j0 + k]);
        float mloc = fmaxf(fmaxf(fmaxf(u[0], u[1]), fmaxf(u[2], u[3])),
                           fmaxf(fmaxf(u[4], u[5]), fmaxf(u[6], u[7])));
        float M2 = fmaxf(m, mloc);
        float acc = 0.f;
#pragma unroll
        for (int k = 0; k < 8; k++) acc += exp2f(u[k] - M2);
        s = s * exp2f(m - M2) + acc;
        m = M2;
    }
    for (int off = 32; off > 0; off >>= 1) {
        float m2 = __shfl_down(m, off);
        float s2 = __shfl_down(s, off);
        float Mx = fmaxf(m, m2);
        s = s * exp2f(m - Mx) + s2 * exp2f(m2 - Mx);
        m = Mx;
    }
    if (lane == 0)
        pot_out[row] = NEG_EPS_LN2 * (m + __log2f(s) - xk) + EPS_NEG_LOGMU;
}

// ---------- fused pass: all 3 pairs in one launch (3072 blocks) ----------
__global__ __launch_bounds__(256) void lse_pass3_kernel(
    const _Float16* __restrict__ Sxy, const _Float16* __restrict__ STxy,
    const _Float16* __restrict__ Sxx, const _Float16* __restrict__ Syy,
    const float* __restrict__ x2, const float* __restrict__ y2,
    float* Pxy0, float* Pxy1, float* Pxx0, float* Pxx1, float* Pyy0, float* Pyy1,
    int odd) {
    __shared__ float gyk[N];
    int pair = blockIdx.x >> 10;
    int rowblk = blockIdx.x & 1023;
    const _Float16* M;
    const float *own, *other, *pin;
    float* pout;
    if (pair == 0) {
        if (odd) { M = Sxy;  own = x2; other = y2; pin = Pxy0; pout = Pxy1; }
        else     { M = STxy; own = y2; other = x2; pin = Pxy1; pout = Pxy0; }
    } else if (pair == 1) {
        M = Sxx; own = x2; other = x2;
        if (odd) { pin = Pxx0; pout = Pxx1; } else { pin = Pxx1; pout = Pxx0; }
    } else {
        M = Syy; own = y2; other = y2;
        if (odd) { pin = Pyy0; pout = Pyy1; } else { pin = Pyy1; pout = Pyy0; }
    }
    lse_row_body(M, pin, other, own, pout, gyk, rowblk);
}

// ---------- single-pair pass (fallback path when ws is small) ----------
__global__ __launch_bounds__(256) void lse_pass_kernel(
    const _Float16* __restrict__ S, const float* __restrict__ pot_in,
    const float* __restrict__ sq_other, const float* __restrict__ sq_own,
    float* __restrict__ pot_out) {
    __shared__ float gyk[N];
    lse_row_body(S, pot_in, sq_other, sq_own, pot_out, gyk, blockIdx.x);
}

// ---------- final: relu( mean(f_xy+g_xy) - 0.5*mean(f_xx+g_xx) - 0.5*mean(f_yy+g_yy) )
__global__ void finalize_kernel(const float* __restrict__ fxy, const float* __restrict__ gxy,
                                const float* __restrict__ fxx, const float* __restrict__ gxx,
                                const float* __restrict__ fyy, const float* __restrict__ gyy,
                                float* __restrict__ out) {
    __shared__ float sb[256];
    float s = 0.f;
    for (int t = threadIdx.x; t < N; t += 256)
        s += (fxy[t] + gxy[t]) - 0.5f * (fxx[t] + gxx[t]) - 0.5f * (fyy[t] + gyy[t]);
    sb[threadIdx.x] = s;
    __syncthreads();
    for (int off = 128; off > 0; off >>= 1) {
        if (threadIdx.x < off) sb[threadIdx.x] += sb[threadIdx.x + off];
        __syncthreads();
    }
    if (threadIdx.x == 0) {
        float v = sb[0] * (1.0f / 4096.0f);
        out[0] = v > 0.f ? v : 0.f;
    }
}

// ---------- fallback helpers ----------
__global__ void pair_reduce_kernel(const float* __restrict__ f, const float* __restrict__ g,
                                   float* __restrict__ ot_slot) {
    __shared__ float sb[256];
    float s = 0.f;
    for (int t = threadIdx.x; t < N; t += 256) s += f[t] + g[t];
    sb[threadIdx.x] = s;
    __syncthreads();
    for (int off = 128; off > 0; off >>= 1) {
        if (threadIdx.x < off) sb[threadIdx.x] += sb[threadIdx.x + off];
        __syncthreads();
    }
    if (threadIdx.x == 0) *ot_slot = sb[0] * (1.0f / 4096.0f);
}

__global__ void final_kernel(const float* __restrict__ ots, float* __restrict__ out) {
    if (threadIdx.x == 0) {
        float v = ots[0] - 0.5f * ots[1] - 0.5f * ots[2];
        out[0] = v > 0.f ? v : 0.f;
    }
}

extern "C" void kernel_launch(void* const* d_in, const int* in_sizes, int n_in,
                              void* d_out, int out_size, void* d_ws, size_t ws_size,
                              hipStream_t stream) {
    const float* x = (const float*)d_in[0];
    const float* y = (const float*)d_in[1];

    const size_t SZ_S = (size_t)N * N * sizeof(_Float16);   // 32 MiB
    const size_t SZ_B = (size_t)N * D * sizeof(__bf16);     // 4 MiB
    // fused path needs 4*SZ_S + 2*SZ_B + small
    const size_t need_fused = 4 * SZ_S + 2 * SZ_B + (size_t)(16 * N + 64) * sizeof(float);

    if (ws_size >= need_fused) {
        // ---------------- fused 3-pair path ----------------
        char* w = (char*)d_ws;
        _Float16* Sxy  = (_Float16*)w; w += SZ_S;
        _Float16* STxy = (_Float16*)w; w += SZ_S;
        _Float16* Sxx  = (_Float16*)w; w += SZ_S;
        _Float16* Syy  = (_Float16*)w; w += SZ_S;
        __bf16* xb = (__bf16*)w;       w += SZ_B;
        __bf16* yb = (__bf16*)w;       w += SZ_B;
        float* x2 = (float*)w;         w += N * sizeof(float);
        float* y2 = (float*)w;         w += N * sizeof(float);
        float* P[6];
        for (int i = 0; i < 6; i++) { P[i] = (float*)w; w += N * sizeof(float); }

        cvt_bf16_kernel<<<(N * D + 255) / 256, 256, 0, stream>>>(x, xb, N * D);
        cvt_bf16_kernel<<<(N * D + 255) / 256, 256, 0, stream>>>(y, yb, N * D);
        sqnorm_kernel<<<N, 64, 0, stream>>>(x, x2);
        sqnorm_kernel<<<N, 64, 0, stream>>>(y, y2);

        dot_gemm_kernel<<<dim3(N / 64, N / 64), 256, 0, stream>>>(xb, yb, Sxy);
        transpose_half_kernel<<<dim3(N / 64, N / 64), 256, 0, stream>>>(Sxy, STxy);
        dot_gemm_kernel<<<dim3(N / 64, N / 64), 256, 0, stream>>>(xb, xb, Sxx);
        dot_gemm_kernel<<<dim3(N / 64, N / 64), 256, 0, stream>>>(yb, yb, Syy);

        hipMemsetAsync(P[0], 0, N * sizeof(float), stream);  // g0_xy
        hipMemsetAsync(P[2], 0, N * sizeof(float), stream);  // g0_xx
        hipMemsetAsync(P[4], 0, N * sizeof(float), stream);  // g0_yy

        for (int p = 1; p <= SINK_PASSES; p++) {
            lse_pass3_kernel<<<3 * (N / 4), 256, 0, stream>>>(
                Sxy, STxy, Sxx, Syy, x2, y2,
                P[0], P[1], P[2], P[3], P[4], P[5], p & 1);
        }
        // after pass 100: f = P[odd-dest] = P1 slots, g = P0 slots
        finalize_kernel<<<1, 256, 0, stream>>>(P[1], P[0], P[3], P[2], P[5], P[4],
                                               (float*)d_out);
    } else {
        // ---------------- sequential fallback (round-2 proven) ----------------
        char* w = (char*)d_ws;
        _Float16* S  = (_Float16*)w; w += SZ_S;
        _Float16* ST = (_Float16*)w; w += SZ_S;
        __bf16* xb = (__bf16*)w;     w += SZ_B;
        __bf16* yb = (__bf16*)w;     w += SZ_B;
        float* x2 = (float*)w;       w += N * sizeof(float);
        float* y2 = (float*)w;       w += N * sizeof(float);
        float* P0 = (float*)w;       w += N * sizeof(float);
        float* P1 = (float*)w;       w += N * sizeof(float);
        float* ots = (float*)w;      w += 4 * sizeof(float);

        cvt_bf16_kernel<<<(N * D + 255) / 256, 256, 0, stream>>>(x, xb, N * D);
        cvt_bf16_kernel<<<(N * D + 255) / 256, 256, 0, stream>>>(y, yb, N * D);
        sqnorm_kernel<<<N, 64, 0, stream>>>(x, x2);
        sqnorm_kernel<<<N, 64, 0, stream>>>(y, y2);

        for (int pair = 0; pair < 3; pair++) {
            const __bf16* a = (pair == 2) ? yb : xb;
            const __bf16* b = (pair == 1) ? xb : yb;
            const float* sqa = (pair == 2) ? y2 : x2;
            const float* sqb = (pair == 1) ? x2 : y2;

            dot_gemm_kernel<<<dim3(N / 64, N / 64), 256, 0, stream>>>(a, b, S);
            const _Float16 *Srow, *Scol;
            if (pair == 0) {
                transpose_half_kernel<<<dim3(N / 64, N / 64), 256, 0, stream>>>(S, ST);
                Srow = S; Scol = ST;
            } else {
                Srow = S; Scol = S;
            }
            hipMemsetAsync(P0, 0, N * sizeof(float), stream);
            for (int p = 1; p <= SINK_PASSES; p++) {
                bool odd = p & 1;
                const _Float16* M = odd ? Srow : Scol;
                const float* own   = odd ? sqa : sqb;
                const float* other = odd ? sqb : sqa;
                const float* pin  = odd ? P0 : P1;
                float* pout       = odd ? P1 : P0;
                lse_pass_kernel<<<N / 4, 256, 0, stream>>>(M, pin, other, own, pout);
            }
            pair_reduce_kernel<<<1, 256, 0, stream>>>(P1, P0, ots + pair);
        }
        final_kernel<<<1, 64, 0, stream>>>(ots, (float*)d_out);
    }
}

// Round 4
// 2580.522 us; speedup vs baseline: 5.5752x; 1.0134x over previous
//
#include <hip/hip_runtime.h>
#include <hip/hip_bf16.h>
#include <math.h>

// Problem constants (fixed by reference: x,y are (4096, 512) fp32)
#define N 4096
#define D 512
#define SINK_PASSES 100           // 50 iterations x (f-update, g-update)

// log-domain constants (base-2 internally; v_exp_f32/v_log_f32 are base-2)
#define K_LOG2 14.426950408889634f          // (1/eps) * log2(e), eps = 0.1
#define TWO_K  28.853900817779268f          // 2 * K_LOG2
#define NEG_EPS_LN2 (-0.06931471805599453f) // -eps * ln(2)
#define EPS_NEG_LOGMU 0.8317766166719343f   // -eps * log_mu = eps * log(4096)

typedef __bf16   bf16x8 __attribute__((ext_vector_type(8)));
typedef _Float16 halfx8 __attribute__((ext_vector_type(8)));
typedef float    floatx4 __attribute__((ext_vector_type(4)));

// ---------- convert fp32 -> bf16 (GEMM inputs) ----------
__global__ void cvt_bf16_kernel(const float* __restrict__ in, __bf16* __restrict__ out, int count) {
    int idx = blockIdx.x * blockDim.x + threadIdx.x;
    if (idx < count) out[idx] = (__bf16)in[idx];
}

// ---------- row squared norms (fp32 inputs, exact) ----------
__global__ void sqnorm_kernel(const float* __restrict__ in, float* __restrict__ out) {
    int row = blockIdx.x;
    const float* p = in + (size_t)row * D;
    float s = 0.f;
    for (int k = threadIdx.x; k < D; k += 64) { float v = p[k]; s += v * v; }
    for (int off = 32; off > 0; off >>= 1) s += __shfl_down(s, off);
    if (threadIdx.x == 0) out[row] = s;
}

// ---------- 128x128-tile GEMM: out = A @ B^T (fp16), writes tile + transposed tile ----------
// LDS-staged, BK=64, XOR-swizzled chunks (c_phys = c ^ (row&7)) for conflict-free
// b128 frag reads. 4 waves in 2x2; each wave 64x64 = 4x4 MFMA 16x16x32 accs.
// Epilogue bounces acc through LDS -> vectorized halfx8 stores (normal + transposed).
// sym=1: upper-triangle blocks only (bx<=by), mirror-write covers the rest
// (diagonal blocks write identical symmetric tile twice - benign).
__global__ __launch_bounds__(256) void gemm128_kernel(
    const __bf16* __restrict__ A, const __bf16* __restrict__ Bm,
    _Float16* __restrict__ out1, _Float16* __restrict__ out2, int sym) {
    if (sym && blockIdx.x > blockIdx.y) return;
    __shared__ char smem[34816];            // max(staging 32KB, epilogue 33.8KB)
    __bf16* ldsA = (__bf16*)smem;           // [128][64] swizzled
    __bf16* ldsB = ldsA + 128 * 64;

    int t = threadIdx.x;
    int w = t >> 6, lane = t & 63;
    int m = lane & 15, q = lane >> 4;
    int wr = w & 1, wc = w >> 1;
    int m0 = blockIdx.x * 128, n0 = blockIdx.y * 128;

    int srow = t >> 1, shalf = t & 1;       // staging: one row-half (64B) per thread
    const bf16x8* gA = (const bf16x8*)(A  + (size_t)(m0 + srow) * D + shalf * 32);
    const bf16x8* gB = (const bf16x8*)(Bm + (size_t)(n0 + srow) * D + shalf * 32);

    floatx4 acc[4][4];
#pragma unroll
    for (int i = 0; i < 4; i++)
#pragma unroll
        for (int j = 0; j < 4; j++) acc[i][j] = (floatx4){0.f, 0.f, 0.f, 0.f};

    for (int slab = 0; slab < 8; slab++) {
        bf16x8 va[4], vb[4];
#pragma unroll
        for (int i = 0; i < 4; i++) {
            va[i] = gA[slab * 8 + i];
            vb[i] = gB[slab * 8 + i];
        }
        __syncthreads();
#pragma unroll
        for (int i = 0; i < 4; i++) {
            int cp = (shalf * 4 + i) ^ (srow & 7);
            *(bf16x8*)(ldsA + srow * 64 + cp * 8) = va[i];
            *(bf16x8*)(ldsB + srow * 64 + cp * 8) = vb[i];
        }
        __syncthreads();
#pragma unroll
        for (int kk = 0; kk < 2; kk++) {
            bf16x8 af[4], bfr[4];
#pragma unroll
            for (int mt = 0; mt < 4; mt++) {
                int cp = (kk * 4 + q) ^ (m & 7);
                af[mt]  = *(const bf16x8*)(ldsA + (wr * 64 + mt * 16 + m) * 64 + cp * 8);
                bfr[mt] = *(const bf16x8*)(ldsB + (wc * 64 + mt * 16 + m) * 64 + cp * 8);
            }
#pragma unroll
            for (int mt = 0; mt < 4; mt++)
#pragma unroll
                for (int nt = 0; nt < 4; nt++)
                    acc[mt][nt] = __builtin_amdgcn_mfma_f32_16x16x32_bf16(
                        af[mt], bfr[nt], acc[mt][nt], 0, 0, 0);
        }
    }

    // epilogue: per-wave 64x66 fp16 tile in LDS (no cross-wave sharing)
    __syncthreads();
    _Float16* et = (_Float16*)smem + w * (64 * 66);
#pragma unroll
    for (int mt = 0; mt < 4; mt++)
#pragma unroll
        for (int nt = 0; nt < 4; nt++)
#pragma unroll
            for (int r = 0; r < 4; r++)
                et[(mt * 16 + q * 4 + r) * 66 + nt * 16 + m] = (_Float16)acc[mt][nt][r];

    int l3 = lane >> 3, c8 = lane & 7;
#pragma unroll
    for (int rr = 0; rr < 8; rr++) {
        int rl = rr * 8 + l3;
        halfx8 v = *(const halfx8*)(et + rl * 66 + c8 * 8);
        *(halfx8*)(out1 + (size_t)(m0 + wr * 64 + rl) * N + n0 + wc * 64 + c8 * 8) = v;
    }
#pragma unroll
    for (int rr = 0; rr < 8; rr++) {
        int rT = rr * 8 + l3;               // tile column = out2 row
        halfx8 v;
#pragma unroll
        for (int k = 0; k < 8; k++) v[k] = et[(c8 * 8 + k) * 66 + rT];
        *(halfx8*)(out2 + (size_t)(n0 + wc * 64 + rT) * N + m0 + wr * 64 + c8 * 8) = v;
    }
}

// ---------- fused Sinkhorn pass: 3 pairs, 2 rows per wave, fully resident ----------
// grid = 3*512 blocks of 256: 6 blocks/CU (LDS 16KB, 24 waves/CU) -> single
// scheduling round, no tail. Two rows/wave share gyk LDS reads and give two
// independent (m,s) chains for latency hiding.
__global__ __launch_bounds__(256) void lse_pass3_kernel(
    const _Float16* __restrict__ Sxy, const _Float16* __restrict__ STxy,
    const _Float16* __restrict__ Sxx, const _Float16* __restrict__ Syy,
    const float* __restrict__ x2, const float* __restrict__ y2,
    float* Pxy0, float* Pxy1, float* Pxx0, float* Pxx1, float* Pyy0, float* Pyy1,
    int odd) {
    __shared__ float gyk[N];
    int pair = blockIdx.x >> 9;
    int blk = blockIdx.x & 511;
    const _Float16* M;
    const float *own, *other, *pin;
    float* pout;
    if (pair == 0) {
        if (odd) { M = Sxy;  own = x2; other = y2; pin = Pxy0; pout = Pxy1; }
        else     { M = STxy; own = y2; other = x2; pin = Pxy1; pout = Pxy0; }
    } else if (pair == 1) {
        M = Sxx; own = x2; other = x2;
        if (odd) { pin = Pxx0; pout = Pxx1; } else { pin = Pxx1; pout = Pxx0; }
    } else {
        M = Syy; own = y2; other = y2;
        if (odd) { pin = Pyy0; pout = Pyy1; } else { pin = Pyy1; pout = Pyy0; }
    }

    // stage gyk = (pot_in - sq_other) * K into LDS (vectorized)
    {
        const floatx4* pi4 = (const floatx4*)pin;
        const floatx4* so4 = (const floatx4*)other;
        floatx4* gy4 = (floatx4*)gyk;
        for (int tt = threadIdx.x; tt < N / 4; tt += 256) {
            floatx4 p = pi4[tt], o = so4[tt];
            floatx4 r;
#pragma unroll
            for (int k = 0; k < 4; k++) r[k] = (p[k] - o[k]) * K_LOG2;
            gy4[tt] = r;
        }
    }
    __syncthreads();

    int wave = threadIdx.x >> 6, lane = threadIdx.x & 63;
    int row0 = blk * 8 + wave * 2;
    const halfx8* rA = (const halfx8*)(M + (size_t)row0 * N);
    const halfx8* rB = rA + (N / 8);

    float mA = -INFINITY, sA = 0.f, mB = -INFINITY, sB = 0.f;
#pragma unroll
    for (int c = 0; c < 8; c++) {
        int chunk = c * 64 + lane;
        halfx8 a = rA[chunk];
        halfx8 b = rB[chunk];
        int j0 = chunk * 8;
        float uA[8], uB[8];
#pragma unroll
        for (int k = 0; k < 8; k++) {
            float gv = gyk[j0 + k];
            uA[k] = fmaf((float)a[k], TWO_K, gv);
            uB[k] = fmaf((float)b[k], TWO_K, gv);
        }
        float mlA = fmaxf(fmaxf(fmaxf(uA[0], uA[1]), fmaxf(uA[2], uA[3])),
                          fmaxf(fmaxf(uA[4], uA[5]), fmaxf(uA[6], uA[7])));
        float mlB = fmaxf(fmaxf(fmaxf(uB[0], uB[1]), fmaxf(uB[2], uB[3])),
                          fmaxf(fmaxf(uB[4], uB[5]), fmaxf(uB[6], uB[7])));
        float MA = fmaxf(mA, mlA), MB = fmaxf(mB, mlB);
        float accA = 0.f, accB = 0.f;
#pragma unroll
        for (int k = 0; k < 8; k++) {
            accA += exp2f(uA[k] - MA);
            accB += exp2f(uB[k] - MB);
        }
        sA = sA * exp2f(mA - MA) + accA; mA = MA;
        sB = sB * exp2f(mB - MB) + accB; mB = MB;
    }
    for (int off = 32; off > 0; off >>= 1) {
        float m2 = __shfl_down(mA, off), s2 = __shfl_down(sA, off);
        float Mx = fmaxf(mA, m2);
        sA = sA * exp2f(mA - Mx) + s2 * exp2f(m2 - Mx);
        mA = Mx;
        m2 = __shfl_down(mB, off); s2 = __shfl_down(sB, off);
        Mx = fmaxf(mB, m2);
        sB = sB * exp2f(mB - Mx) + s2 * exp2f(m2 - Mx);
        mB = Mx;
    }
    if (lane == 0) {
        float xkA = own[row0] * K_LOG2;
        float xkB = own[row0 + 1] * K_LOG2;
        pout[row0]     = NEG_EPS_LN2 * (mA + __log2f(sA) - xkA) + EPS_NEG_LOGMU;
        pout[row0 + 1] = NEG_EPS_LN2 * (mB + __log2f(sB) - xkB) + EPS_NEG_LOGMU;
    }
}

// ---------- final: relu( mean(f_xy+g_xy) - 0.5*mean(f_xx+g_xx) - 0.5*mean(f_yy+g_yy) )
__global__ void finalize_kernel(const float* __restrict__ fxy, const float* __restrict__ gxy,
                                const float* __restrict__ fxx, const float* __restrict__ gxx,
                                const float* __restrict__ fyy, const float* __restrict__ gyy,
                                float* __restrict__ out) {
    __shared__ float sb[256];
    float s = 0.f;
    for (int t = threadIdx.x; t < N; t += 256)
        s += (fxy[t] + gxy[t]) - 0.5f * (fxx[t] + gxx[t]) - 0.5f * (fyy[t] + gyy[t]);
    sb[threadIdx.x] = s;
    __syncthreads();
    for (int off = 128; off > 0; off >>= 1) {
        if (threadIdx.x < off) sb[threadIdx.x] += sb[threadIdx.x + off];
        __syncthreads();
    }
    if (threadIdx.x == 0) {
        float v = sb[0] * (1.0f / 4096.0f);
        out[0] = v > 0.f ? v : 0.f;
    }
}

extern "C" void kernel_launch(void* const* d_in, const int* in_sizes, int n_in,
                              void* d_out, int out_size, void* d_ws, size_t ws_size,
                              hipStream_t stream) {
    const float* x = (const float*)d_in[0];
    const float* y = (const float*)d_in[1];

    const size_t SZ_S = (size_t)N * N * sizeof(_Float16);   // 32 MiB
    const size_t SZ_B = (size_t)N * D * sizeof(__bf16);     // 4 MiB

    char* w = (char*)d_ws;
    _Float16* Sxy  = (_Float16*)w; w += SZ_S;
    _Float16* STxy = (_Float16*)w; w += SZ_S;
    _Float16* Sxx  = (_Float16*)w; w += SZ_S;
    _Float16* Syy  = (_Float16*)w; w += SZ_S;
    __bf16* xb = (__bf16*)w;       w += SZ_B;
    __bf16* yb = (__bf16*)w;       w += SZ_B;
    float* x2 = (float*)w;         w += N * sizeof(float);
    float* y2 = (float*)w;         w += N * sizeof(float);
    float* P[6];
    for (int i = 0; i < 6; i++) { P[i] = (float*)w; w += N * sizeof(float); }

    cvt_bf16_kernel<<<(N * D + 255) / 256, 256, 0, stream>>>(x, xb, N * D);
    cvt_bf16_kernel<<<(N * D + 255) / 256, 256, 0, stream>>>(y, yb, N * D);
    sqnorm_kernel<<<N, 64, 0, stream>>>(x, x2);
    sqnorm_kernel<<<N, 64, 0, stream>>>(y, y2);

    // GEMMs: xy writes S + S^T; xx/yy upper-triangle with mirror writes
    gemm128_kernel<<<dim3(32, 32), 256, 0, stream>>>(xb, yb, Sxy, STxy, 0);
    gemm128_kernel<<<dim3(32, 32), 256, 0, stream>>>(xb, xb, Sxx, Sxx, 1);
    gemm128_kernel<<<dim3(32, 32), 256, 0, stream>>>(yb, yb, Syy, Syy, 1);

    hipMemsetAsync(P[0], 0, N * sizeof(float), stream);  // g0_xy
    hipMemsetAsync(P[2], 0, N * sizeof(float), stream);  // g0_xx
    hipMemsetAsync(P[4], 0, N * sizeof(float), stream);  // g0_yy

    for (int p = 1; p <= SINK_PASSES; p++) {
        lse_pass3_kernel<<<3 * (N / 8), 256, 0, stream>>>(
            Sxy, STxy, Sxx, Syy, x2, y2,
            P[0], P[1], P[2], P[3], P[4], P[5], p & 1);
    }
    // after pass 100: f = P1 slots, g = P0 slots
    finalize_kernel<<<1, 256, 0, stream>>>(P[1], P[0], P[3], P[2], P[5], P[4],
                                           (float*)d_out);
}

// Round 5
// 1826.357 us; speedup vs baseline: 7.8774x; 1.4129x over previous
//
#include <hip/hip_runtime.h>
#include <hip/hip_bf16.h>
#include <math.h>

// Problem constants (fixed by reference: x,y are (4096, 512) fp32)
#define N 4096
#define D 512
#define SINK_PASSES 100           // 50 iterations x (f-update, g-update)

// log-domain constants (base-2 internally; v_exp_f32/v_log_f32 are base-2)
#define K_LOG2 14.426950408889634f          // (1/eps) * log2(e), eps = 0.1
#define TWO_K  28.853900817779268f          // 2 * K_LOG2
#define NEG_EPS_LN2 (-0.06931471805599453f) // -eps * ln(2)
#define EPS_NEG_LOGMU 0.8317766166719343f   // -eps * log_mu = eps * log(4096)

// Sparse-candidate machinery: entries with u < rowmax - MARGIN (log2 units)
// contribute < 2^-MARGIN each; MARGIN=600 also covers potential drift of
// ~41 units between candidate rebuilds (rebuild every 8 passes).
#define CAP 512
#define MARGIN 600.0f

typedef __bf16   bf16x8 __attribute__((ext_vector_type(8)));
typedef _Float16 halfx8 __attribute__((ext_vector_type(8)));
typedef float    floatx4 __attribute__((ext_vector_type(4)));
typedef unsigned short ushortx8v __attribute__((ext_vector_type(8)));

// ---------- convert fp32 -> bf16 (GEMM inputs) ----------
__global__ void cvt_bf16_kernel(const float* __restrict__ in, __bf16* __restrict__ out, int count) {
    int idx = blockIdx.x * blockDim.x + threadIdx.x;
    if (idx < count) out[idx] = (__bf16)in[idx];
}

// ---------- row squared norms (fp32 inputs, exact) ----------
__global__ void sqnorm_kernel(const float* __restrict__ in, float* __restrict__ out) {
    int row = blockIdx.x;
    const float* p = in + (size_t)row * D;
    float s = 0.f;
    for (int k = threadIdx.x; k < D; k += 64) { float v = p[k]; s += v * v; }
    for (int off = 32; off > 0; off >>= 1) s += __shfl_down(s, off);
    if (threadIdx.x == 0) out[row] = s;
}

// ---------- 128x128-tile GEMM: out = A @ B^T (fp16), writes tile + transposed tile ----------
// (round-4 proven; sym=1 computes upper-triangle blocks + mirror writes)
__global__ __launch_bounds__(256) void gemm128_kernel(
    const __bf16* __restrict__ A, const __bf16* __restrict__ Bm,
    _Float16* __restrict__ out1, _Float16* __restrict__ out2, int sym) {
    if (sym && blockIdx.x > blockIdx.y) return;
    __shared__ char smem[34816];
    __bf16* ldsA = (__bf16*)smem;           // [128][64] swizzled
    __bf16* ldsB = ldsA + 128 * 64;

    int t = threadIdx.x;
    int w = t >> 6, lane = t & 63;
    int m = lane & 15, q = lane >> 4;
    int wr = w & 1, wc = w >> 1;
    int m0 = blockIdx.x * 128, n0 = blockIdx.y * 128;

    int srow = t >> 1, shalf = t & 1;
    const bf16x8* gA = (const bf16x8*)(A  + (size_t)(m0 + srow) * D + shalf * 32);
    const bf16x8* gB = (const bf16x8*)(Bm + (size_t)(n0 + srow) * D + shalf * 32);

    floatx4 acc[4][4];
#pragma unroll
    for (int i = 0; i < 4; i++)
#pragma unroll
        for (int j = 0; j < 4; j++) acc[i][j] = (floatx4){0.f, 0.f, 0.f, 0.f};

    for (int slab = 0; slab < 8; slab++) {
        bf16x8 va[4], vb[4];
#pragma unroll
        for (int i = 0; i < 4; i++) {
            va[i] = gA[slab * 8 + i];
            vb[i] = gB[slab * 8 + i];
        }
        __syncthreads();
#pragma unroll
        for (int i = 0; i < 4; i++) {
            int cp = (shalf * 4 + i) ^ (srow & 7);
            *(bf16x8*)(ldsA + srow * 64 + cp * 8) = va[i];
            *(bf16x8*)(ldsB + srow * 64 + cp * 8) = vb[i];
        }
        __syncthreads();
#pragma unroll
        for (int kk = 0; kk < 2; kk++) {
            bf16x8 af[4], bfr[4];
#pragma unroll
            for (int mt = 0; mt < 4; mt++) {
                int cp = (kk * 4 + q) ^ (m & 7);
                af[mt]  = *(const bf16x8*)(ldsA + (wr * 64 + mt * 16 + m) * 64 + cp * 8);
                bfr[mt] = *(const bf16x8*)(ldsB + (wc * 64 + mt * 16 + m) * 64 + cp * 8);
            }
#pragma unroll
            for (int mt = 0; mt < 4; mt++)
#pragma unroll
                for (int nt = 0; nt < 4; nt++)
                    acc[mt][nt] = __builtin_amdgcn_mfma_f32_16x16x32_bf16(
                        af[mt], bfr[nt], acc[mt][nt], 0, 0, 0);
        }
    }

    __syncthreads();
    _Float16* et = (_Float16*)smem + w * (64 * 66);
#pragma unroll
    for (int mt = 0; mt < 4; mt++)
#pragma unroll
        for (int nt = 0; nt < 4; nt++)
#pragma unroll
            for (int r = 0; r < 4; r++)
                et[(mt * 16 + q * 4 + r) * 66 + nt * 16 + m] = (_Float16)acc[mt][nt][r];

    int l3 = lane >> 3, c8 = lane & 7;
#pragma unroll
    for (int rr = 0; rr < 8; rr++) {
        int rl = rr * 8 + l3;
        halfx8 v = *(const halfx8*)(et + rl * 66 + c8 * 8);
        *(halfx8*)(out1 + (size_t)(m0 + wr * 64 + rl) * N + n0 + wc * 64 + c8 * 8) = v;
    }
#pragma unroll
    for (int rr = 0; rr < 8; rr++) {
        int rT = rr * 8 + l3;
        halfx8 v;
#pragma unroll
        for (int k = 0; k < 8; k++) v[k] = et[(c8 * 8 + k) * 66 + rT];
        *(halfx8*)(out2 + (size_t)(n0 + wc * 64 + rT) * N + m0 + wr * 64 + c8 * 8) = v;
    }
}

// ---------- full Sinkhorn pass (3 pairs, 1 row/wave, 3072 blocks) ----------
// BUILD=1: additionally collect candidates u >= prevmax - MARGIN into cand[],
// and write cnt[]. Every variant stores this pass's row max into prevmax[].
template<int BUILD>
__global__ __launch_bounds__(256) void lse_full3_kernel(
    const _Float16* __restrict__ Sxy, const _Float16* __restrict__ STxy,
    const _Float16* __restrict__ Sxx, const _Float16* __restrict__ Syy,
    const float* __restrict__ x2, const float* __restrict__ y2,
    float* __restrict__ Pxy0, float* __restrict__ Pxy1,
    float* __restrict__ Pxx0, float* __restrict__ Pxx1,
    float* __restrict__ Pyy0, float* __restrict__ Pyy1,
    int odd,
    unsigned int* __restrict__ cand, int* __restrict__ cnt,
    float* __restrict__ prevmax) {
    __shared__ float gyk[N];
    __shared__ int hc[4];
    int pair = blockIdx.x >> 10;
    int blk = blockIdx.x & 1023;
    const _Float16* M;
    const float *own, *other, *pin;
    float* pout;
    if (pair == 0) {
        if (odd) { M = Sxy;  own = x2; other = y2; pin = Pxy0; pout = Pxy1; }
        else     { M = STxy; own = y2; other = x2; pin = Pxy1; pout = Pxy0; }
    } else if (pair == 1) {
        M = Sxx; own = x2; other = x2;
        if (odd) { pin = Pxx0; pout = Pxx1; } else { pin = Pxx1; pout = Pxx0; }
    } else {
        M = Syy; own = y2; other = y2;
        if (odd) { pin = Pyy0; pout = Pyy1; } else { pin = Pyy1; pout = Pyy0; }
    }

    int wave = threadIdx.x >> 6, lane = threadIdx.x & 63;
    if (BUILD && lane == 0) hc[wave] = 0;

    {   // stage gyk = (pot_in - sq_other) * K
        const floatx4* pi4 = (const floatx4*)pin;
        const floatx4* so4 = (const floatx4*)other;
        floatx4* gy4 = (floatx4*)gyk;
        for (int tt = threadIdx.x; tt < N / 4; tt += 256) {
            floatx4 p = pi4[tt], o = so4[tt];
            floatx4 r;
#pragma unroll
            for (int k = 0; k < 4; k++) r[k] = (p[k] - o[k]) * K_LOG2;
            gy4[tt] = r;
        }
    }
    __syncthreads();

    int row = blk * 4 + wave;
    int set = pair * 2 + (odd ? 0 : 1);
    int idx = set * N + row;
    float thr = 0.f;
    size_t cbase = 0;
    if (BUILD) { thr = prevmax[idx] - MARGIN; cbase = (size_t)idx * CAP; }

    const halfx8* srow = (const halfx8*)(M + (size_t)row * N);
    float m = -INFINITY, s = 0.f;
#pragma unroll
    for (int c = 0; c < 8; c++) {
        int chunk = c * 64 + lane;
        halfx8 sv = srow[chunk];
        int j0 = chunk * 8;
        float u[8];
#pragma unroll
        for (int k = 0; k < 8; k++)
            u[k] = fmaf((float)sv[k], TWO_K, gyk[j0 + k]);
        if (BUILD) {
            ushortx8v sb = __builtin_bit_cast(ushortx8v, sv);
#pragma unroll
            for (int k = 0; k < 8; k++) {
                if (u[k] >= thr) {
                    int slot = atomicAdd(&hc[wave], 1);
                    if (slot < CAP)
                        cand[cbase + slot] = ((unsigned int)(j0 + k) << 16) | (unsigned int)sb[k];
                }
            }
        }
        float mloc = fmaxf(fmaxf(fmaxf(u[0], u[1]), fmaxf(u[2], u[3])),
                           fmaxf(fmaxf(u[4], u[5]), fmaxf(u[6], u[7])));
        float M2 = fmaxf(m, mloc);
        float acc = 0.f;
#pragma unroll
        for (int k = 0; k < 8; k++) acc += exp2f(u[k] - M2);
        s = s * exp2f(m - M2) + acc;
        m = M2;
    }
    for (int off = 32; off > 0; off >>= 1) {
        float m2 = __shfl_down(m, off), s2 = __shfl_down(s, off);
        float Mx = fmaxf(m, m2);
        s = s * exp2f(m - Mx) + s2 * exp2f(m2 - Mx);
        m = Mx;
    }
    if (lane == 0) {
        float xk = own[row] * K_LOG2;
        pout[row] = NEG_EPS_LN2 * (m + __log2f(s) - xk) + EPS_NEG_LOGMU;
        prevmax[idx] = m;
        if (BUILD) cnt[idx] = hc[wave];
    }
}

// ---------- sparse Sinkhorn pass: LSE over candidate entries only ----------
// 768 blocks; each wave handles 4 rows, candidates lane-parallel.
// Fallback to dense row scan when cnt==0 or cnt>CAP (overflow) — correctness
// never depends on the margin holding.
__global__ __launch_bounds__(256) void lse_sparse3_kernel(
    const _Float16* __restrict__ Sxy, const _Float16* __restrict__ STxy,
    const _Float16* __restrict__ Sxx, const _Float16* __restrict__ Syy,
    const float* __restrict__ x2, const float* __restrict__ y2,
    float* __restrict__ Pxy0, float* __restrict__ Pxy1,
    float* __restrict__ Pxx0, float* __restrict__ Pxx1,
    float* __restrict__ Pyy0, float* __restrict__ Pyy1,
    int odd,
    const unsigned int* __restrict__ cand, const int* __restrict__ cnt,
    float* __restrict__ prevmax) {
    __shared__ float gyk[N];
    int pair = blockIdx.x >> 8;     // 256 blocks per pair
    int pblk = blockIdx.x & 255;
    const _Float16* M;
    const float *own, *other, *pin;
    float* pout;
    if (pair == 0) {
        if (odd) { M = Sxy;  own = x2; other = y2; pin = Pxy0; pout = Pxy1; }
        else     { M = STxy; own = y2; other = x2; pin = Pxy1; pout = Pxy0; }
    } else if (pair == 1) {
        M = Sxx; own = x2; other = x2;
        if (odd) { pin = Pxx0; pout = Pxx1; } else { pin = Pxx1; pout = Pxx0; }
    } else {
        M = Syy; own = y2; other = y2;
        if (odd) { pin = Pyy0; pout = Pyy1; } else { pin = Pyy1; pout = Pyy0; }
    }

    {   // stage gyk
        const floatx4* pi4 = (const floatx4*)pin;
        const floatx4* so4 = (const floatx4*)other;
        floatx4* gy4 = (floatx4*)gyk;
        for (int tt = threadIdx.x; tt < N / 4; tt += 256) {
            floatx4 p = pi4[tt], o = so4[tt];
            floatx4 r;
#pragma unroll
            for (int k = 0; k < 4; k++) r[k] = (p[k] - o[k]) * K_LOG2;
            gy4[tt] = r;
        }
    }
    __syncthreads();

    int wave = threadIdx.x >> 6, lane = threadIdx.x & 63;
    int set = pair * 2 + (odd ? 0 : 1);

    for (int i = 0; i < 4; i++) {
        int row = pblk * 16 + wave * 4 + i;
        int idx = set * N + row;
        int c = cnt[idx];
        float m = -INFINITY, s = 0.f;
        if (c >= 1 && c <= CAP) {
            size_t cbase = (size_t)idx * CAP;
            for (int b = 0; b < c; b += 64) {
                int t = b + lane;
                if (t < c) {
                    unsigned int pk = cand[cbase + t];
                    _Float16 h = __builtin_bit_cast(_Float16, (unsigned short)(pk & 0xffffu));
                    float u = fmaf((float)h, TWO_K, gyk[pk >> 16]);
                    float Mx = fmaxf(m, u);
                    s = s * exp2f(m - Mx) + exp2f(u - Mx);
                    m = Mx;
                }
            }
        } else {
            const halfx8* rowp = (const halfx8*)(M + (size_t)row * N);
            for (int ch = lane; ch < N / 8; ch += 64) {
                halfx8 sv = rowp[ch];
                int j0 = ch * 8;
                float u[8];
#pragma unroll
                for (int k = 0; k < 8; k++)
                    u[k] = fmaf((float)sv[k], TWO_K, gyk[j0 + k]);
                float mloc = fmaxf(fmaxf(fmaxf(u[0], u[1]), fmaxf(u[2], u[3])),
                                   fmaxf(fmaxf(u[4], u[5]), fmaxf(u[6], u[7])));
                float M2 = fmaxf(m, mloc);
                float acc = 0.f;
#pragma unroll
                for (int k = 0; k < 8; k++) acc += exp2f(u[k] - M2);
                s = s * exp2f(m - M2) + acc;
                m = M2;
            }
        }
        // wave merge with -inf guards (empty lanes)
        for (int off = 32; off > 0; off >>= 1) {
            float m2 = __shfl_down(m, off), s2 = __shfl_down(s, off);
            float Mx = fmaxf(m, m2);
            float a1 = (m  == -INFINITY) ? 0.f : s  * exp2f(m  - Mx);
            float a2 = (m2 == -INFINITY) ? 0.f : s2 * exp2f(m2 - Mx);
            m = Mx; s = a1 + a2;
        }
        if (lane == 0) {
            float xk = own[row] * K_LOG2;
            pout[row] = NEG_EPS_LN2 * (m + __log2f(s) - xk) + EPS_NEG_LOGMU;
            prevmax[idx] = m;
        }
    }
}

// ---------- final: relu( mean(f_xy+g_xy) - 0.5*mean(f_xx+g_xx) - 0.5*mean(f_yy+g_yy) )
__global__ void finalize_kernel(const float* __restrict__ fxy, const float* __restrict__ gxy,
                                const float* __restrict__ fxx, const float* __restrict__ gxx,
                                const float* __restrict__ fyy, const float* __restrict__ gyy,
                                float* __restrict__ out) {
    __shared__ float sb[256];
    float s = 0.f;
    for (int t = threadIdx.x; t < N; t += 256)
        s += (fxy[t] + gxy[t]) - 0.5f * (fxx[t] + gxx[t]) - 0.5f * (fyy[t] + gyy[t]);
    sb[threadIdx.x] = s;
    __syncthreads();
    for (int off = 128; off > 0; off >>= 1) {
        if (threadIdx.x < off) sb[threadIdx.x] += sb[threadIdx.x + off];
        __syncthreads();
    }
    if (threadIdx.x == 0) {
        float v = sb[0] * (1.0f / 4096.0f);
        out[0] = v > 0.f ? v : 0.f;
    }
}

extern "C" void kernel_launch(void* const* d_in, const int* in_sizes, int n_in,
                              void* d_out, int out_size, void* d_ws, size_t ws_size,
                              hipStream_t stream) {
    const float* x = (const float*)d_in[0];
    const float* y = (const float*)d_in[1];

    const size_t SZ_S = (size_t)N * N * sizeof(_Float16);   // 32 MiB
    const size_t SZ_B = (size_t)N * D * sizeof(__bf16);     // 4 MiB
    const size_t SZ_CAND = (size_t)6 * N * CAP * sizeof(unsigned int);  // 48 MiB

    char* w = (char*)d_ws;
    _Float16* Sxy  = (_Float16*)w; w += SZ_S;
    _Float16* STxy = (_Float16*)w; w += SZ_S;
    _Float16* Sxx  = (_Float16*)w; w += SZ_S;
    _Float16* Syy  = (_Float16*)w; w += SZ_S;
    __bf16* xb = (__bf16*)w;       w += SZ_B;
    __bf16* yb = (__bf16*)w;       w += SZ_B;
    unsigned int* cand = (unsigned int*)w; w += SZ_CAND;
    int* cnt = (int*)w;            w += (size_t)6 * N * sizeof(int);
    float* prevmax = (float*)w;    w += (size_t)6 * N * sizeof(float);
    float* x2 = (float*)w;         w += N * sizeof(float);
    float* y2 = (float*)w;         w += N * sizeof(float);
    float* P[6];
    for (int i = 0; i < 6; i++) { P[i] = (float*)w; w += N * sizeof(float); }

    const size_t need = (size_t)(w - (char*)d_ws);
    const bool sparse_ok = (ws_size >= need);

    cvt_bf16_kernel<<<(N * D + 255) / 256, 256, 0, stream>>>(x, xb, N * D);
    cvt_bf16_kernel<<<(N * D + 255) / 256, 256, 0, stream>>>(y, yb, N * D);
    sqnorm_kernel<<<N, 64, 0, stream>>>(x, x2);
    sqnorm_kernel<<<N, 64, 0, stream>>>(y, y2);

    gemm128_kernel<<<dim3(32, 32), 256, 0, stream>>>(xb, yb, Sxy, STxy, 0);
    gemm128_kernel<<<dim3(32, 32), 256, 0, stream>>>(xb, xb, Sxx, Sxx, 1);
    gemm128_kernel<<<dim3(32, 32), 256, 0, stream>>>(yb, yb, Syy, Syy, 1);

    hipMemsetAsync(P[0], 0, N * sizeof(float), stream);  // g0_xy
    hipMemsetAsync(P[2], 0, N * sizeof(float), stream);  // g0_xx
    hipMemsetAsync(P[4], 0, N * sizeof(float), stream);  // g0_yy

    for (int p = 1; p <= SINK_PASSES; p++) {
        int odd = p & 1;
        bool full, build;
        if (!sparse_ok) { full = true; build = false; }
        else if (p <= 24) { full = true; build = false; }
        else { int ph = (p - 25) % 8; full = build = (ph < 2); }

        if (full) {
            if (build)
                lse_full3_kernel<1><<<3 * (N / 4), 256, 0, stream>>>(
                    Sxy, STxy, Sxx, Syy, x2, y2,
                    P[0], P[1], P[2], P[3], P[4], P[5], odd, cand, cnt, prevmax);
            else
                lse_full3_kernel<0><<<3 * (N / 4), 256, 0, stream>>>(
                    Sxy, STxy, Sxx, Syy, x2, y2,
                    P[0], P[1], P[2], P[3], P[4], P[5], odd, cand, cnt, prevmax);
        } else {
            lse_sparse3_kernel<<<3 * 256, 256, 0, stream>>>(
                Sxy, STxy, Sxx, Syy, x2, y2,
                P[0], P[1], P[2], P[3], P[4], P[5], odd, cand, cnt, prevmax);
        }
    }
    finalize_kernel<<<1, 256, 0, stream>>>(P[1], P[0], P[3], P[2], P[5], P[4],
                                           (float*)d_out);
}

// Round 6
// 1683.994 us; speedup vs baseline: 8.5433x; 1.0845x over previous
//
#include <hip/hip_runtime.h>
#include <hip/hip_bf16.h>
#include <math.h>

// Problem constants (fixed by reference: x,y are (4096, 512) fp32)
#define N 4096
#define D 512
#define SINK_PASSES 100           // 50 iterations x (f-update, g-update)

// log-domain constants (base-2 internally; v_exp_f32/v_log_f32 are base-2)
#define K_LOG2 14.426950408889634f          // (1/eps) * log2(e), eps = 0.1
#define TWO_K  28.853900817779268f          // 2 * K_LOG2
#define NEG_EPS_LN2 (-0.06931471805599453f) // -eps * ln(2)
#define EPS_NEG_LOGMU 0.8317766166719343f   // -eps * log_mu = eps * log(4096)

// Sparse-candidate machinery: entries with u < rowmax - MARGIN (log2 units)
// contribute < 2^-MARGIN each; MARGIN=600 also covers potential drift of
// ~41 units between candidate rebuilds (rebuild every 16 passes).
#define CAP 512
#define MARGIN 600.0f

typedef __bf16   bf16x8 __attribute__((ext_vector_type(8)));
typedef _Float16 halfx8 __attribute__((ext_vector_type(8)));
typedef float    floatx4 __attribute__((ext_vector_type(4)));
typedef unsigned short ushortx8v __attribute__((ext_vector_type(8)));

// ---------- convert fp32 -> bf16 (GEMM inputs) ----------
__global__ void cvt_bf16_kernel(const float* __restrict__ in, __bf16* __restrict__ out, int count) {
    int idx = blockIdx.x * blockDim.x + threadIdx.x;
    if (idx < count) out[idx] = (__bf16)in[idx];
}

// ---------- row squared norms (fp32 inputs, exact) ----------
__global__ void sqnorm_kernel(const float* __restrict__ in, float* __restrict__ out) {
    int row = blockIdx.x;
    const float* p = in + (size_t)row * D;
    float s = 0.f;
    for (int k = threadIdx.x; k < D; k += 64) { float v = p[k]; s += v * v; }
    for (int off = 32; off > 0; off >>= 1) s += __shfl_down(s, off);
    if (threadIdx.x == 0) out[row] = s;
}

// ---------- 128x128-tile GEMM: out = A @ B^T (fp16), writes tile + transposed tile ----------
// (round-4 proven; sym=1 computes upper-triangle blocks + mirror writes)
__global__ __launch_bounds__(256) void gemm128_kernel(
    const __bf16* __restrict__ A, const __bf16* __restrict__ Bm,
    _Float16* __restrict__ out1, _Float16* __restrict__ out2, int sym) {
    if (sym && blockIdx.x > blockIdx.y) return;
    __shared__ char smem[34816];
    __bf16* ldsA = (__bf16*)smem;           // [128][64] swizzled
    __bf16* ldsB = ldsA + 128 * 64;

    int t = threadIdx.x;
    int w = t >> 6, lane = t & 63;
    int m = lane & 15, q = lane >> 4;
    int wr = w & 1, wc = w >> 1;
    int m0 = blockIdx.x * 128, n0 = blockIdx.y * 128;

    int srow = t >> 1, shalf = t & 1;
    const bf16x8* gA = (const bf16x8*)(A  + (size_t)(m0 + srow) * D + shalf * 32);
    const bf16x8* gB = (const bf16x8*)(Bm + (size_t)(n0 + srow) * D + shalf * 32);

    floatx4 acc[4][4];
#pragma unroll
    for (int i = 0; i < 4; i++)
#pragma unroll
        for (int j = 0; j < 4; j++) acc[i][j] = (floatx4){0.f, 0.f, 0.f, 0.f};

    for (int slab = 0; slab < 8; slab++) {
        bf16x8 va[4], vb[4];
#pragma unroll
        for (int i = 0; i < 4; i++) {
            va[i] = gA[slab * 8 + i];
            vb[i] = gB[slab * 8 + i];
        }
        __syncthreads();
#pragma unroll
        for (int i = 0; i < 4; i++) {
            int cp = (shalf * 4 + i) ^ (srow & 7);
            *(bf16x8*)(ldsA + srow * 64 + cp * 8) = va[i];
            *(bf16x8*)(ldsB + srow * 64 + cp * 8) = vb[i];
        }
        __syncthreads();
#pragma unroll
        for (int kk = 0; kk < 2; kk++) {
            bf16x8 af[4], bfr[4];
#pragma unroll
            for (int mt = 0; mt < 4; mt++) {
                int cp = (kk * 4 + q) ^ (m & 7);
                af[mt]  = *(const bf16x8*)(ldsA + (wr * 64 + mt * 16 + m) * 64 + cp * 8);
                bfr[mt] = *(const bf16x8*)(ldsB + (wc * 64 + mt * 16 + m) * 64 + cp * 8);
            }
#pragma unroll
            for (int mt = 0; mt < 4; mt++)
#pragma unroll
                for (int nt = 0; nt < 4; nt++)
                    acc[mt][nt] = __builtin_amdgcn_mfma_f32_16x16x32_bf16(
                        af[mt], bfr[nt], acc[mt][nt], 0, 0, 0);
        }
    }

    __syncthreads();
    _Float16* et = (_Float16*)smem + w * (64 * 66);
#pragma unroll
    for (int mt = 0; mt < 4; mt++)
#pragma unroll
        for (int nt = 0; nt < 4; nt++)
#pragma unroll
            for (int r = 0; r < 4; r++)
                et[(mt * 16 + q * 4 + r) * 66 + nt * 16 + m] = (_Float16)acc[mt][nt][r];

    int l3 = lane >> 3, c8 = lane & 7;
#pragma unroll
    for (int rr = 0; rr < 8; rr++) {
        int rl = rr * 8 + l3;
        halfx8 v = *(const halfx8*)(et + rl * 66 + c8 * 8);
        *(halfx8*)(out1 + (size_t)(m0 + wr * 64 + rl) * N + n0 + wc * 64 + c8 * 8) = v;
    }
#pragma unroll
    for (int rr = 0; rr < 8; rr++) {
        int rT = rr * 8 + l3;
        halfx8 v;
#pragma unroll
        for (int k = 0; k < 8; k++) v[k] = et[(c8 * 8 + k) * 66 + rT];
        *(halfx8*)(out2 + (size_t)(n0 + wc * 64 + rT) * N + m0 + wr * 64 + c8 * 8) = v;
    }
}

// ---------- full Sinkhorn pass (3 pairs, 1 row/wave, 3072 blocks) ----------
// BUILD=1: collect candidates u >= prevmax - MARGIN via ballot compaction
// (atomic-free, wave-uniform running count). Every variant stores this pass's
// row max into prevmax[].
template<int BUILD>
__global__ __launch_bounds__(256) void lse_full3_kernel(
    const _Float16* __restrict__ Sxy, const _Float16* __restrict__ STxy,
    const _Float16* __restrict__ Sxx, const _Float16* __restrict__ Syy,
    const float* __restrict__ x2, const float* __restrict__ y2,
    float* __restrict__ Pxy0, float* __restrict__ Pxy1,
    float* __restrict__ Pxx0, float* __restrict__ Pxx1,
    float* __restrict__ Pyy0, float* __restrict__ Pyy1,
    int odd,
    unsigned int* __restrict__ cand, int* __restrict__ cnt,
    float* __restrict__ prevmax) {
    __shared__ float gyk[N];
    int pair = blockIdx.x >> 10;
    int blk = blockIdx.x & 1023;
    const _Float16* M;
    const float *own, *other, *pin;
    float* pout;
    if (pair == 0) {
        if (odd) { M = Sxy;  own = x2; other = y2; pin = Pxy0; pout = Pxy1; }
        else     { M = STxy; own = y2; other = x2; pin = Pxy1; pout = Pxy0; }
    } else if (pair == 1) {
        M = Sxx; own = x2; other = x2;
        if (odd) { pin = Pxx0; pout = Pxx1; } else { pin = Pxx1; pout = Pxx0; }
    } else {
        M = Syy; own = y2; other = y2;
        if (odd) { pin = Pyy0; pout = Pyy1; } else { pin = Pyy1; pout = Pyy0; }
    }

    int wave = threadIdx.x >> 6, lane = threadIdx.x & 63;

    {   // stage gyk = (pot_in - sq_other) * K
        const floatx4* pi4 = (const floatx4*)pin;
        const floatx4* so4 = (const floatx4*)other;
        floatx4* gy4 = (floatx4*)gyk;
        for (int tt = threadIdx.x; tt < N / 4; tt += 256) {
            floatx4 p = pi4[tt], o = so4[tt];
            floatx4 r;
#pragma unroll
            for (int k = 0; k < 4; k++) r[k] = (p[k] - o[k]) * K_LOG2;
            gy4[tt] = r;
        }
    }
    __syncthreads();

    int row = blk * 4 + wave;
    int set = pair * 2 + (odd ? 0 : 1);
    int idx = set * N + row;
    float thr = 0.f;
    size_t cbase = 0;
    int ncand = 0;
    unsigned long long lt_mask = (1ull << lane) - 1ull;
    if (BUILD) { thr = prevmax[idx] - MARGIN; cbase = (size_t)idx * CAP; }

    const halfx8* srow = (const halfx8*)(M + (size_t)row * N);
    float m = -INFINITY, s = 0.f;
#pragma unroll
    for (int c = 0; c < 8; c++) {
        int chunk = c * 64 + lane;
        halfx8 sv = srow[chunk];
        int j0 = chunk * 8;
        float u[8];
#pragma unroll
        for (int k = 0; k < 8; k++)
            u[k] = fmaf((float)sv[k], TWO_K, gyk[j0 + k]);
        if (BUILD) {
            ushortx8v sb = __builtin_bit_cast(ushortx8v, sv);
#pragma unroll
            for (int k = 0; k < 8; k++) {
                bool hit = (u[k] >= thr);
                unsigned long long mask = __ballot(hit);
                if (hit) {
                    int slot = ncand + __popcll(mask & lt_mask);
                    if (slot < CAP)
                        cand[cbase + slot] = ((unsigned int)(j0 + k) << 16) | (unsigned int)sb[k];
                }
                ncand += (int)__popcll(mask);
            }
        }
        float mloc = fmaxf(fmaxf(fmaxf(u[0], u[1]), fmaxf(u[2], u[3])),
                           fmaxf(fmaxf(u[4], u[5]), fmaxf(u[6], u[7])));
        float M2 = fmaxf(m, mloc);
        float acc = 0.f;
#pragma unroll
        for (int k = 0; k < 8; k++) acc += exp2f(u[k] - M2);
        s = s * exp2f(m - M2) + acc;
        m = M2;
    }
    for (int off = 32; off > 0; off >>= 1) {
        float m2 = __shfl_down(m, off), s2 = __shfl_down(s, off);
        float Mx = fmaxf(m, m2);
        s = s * exp2f(m - Mx) + s2 * exp2f(m2 - Mx);
        m = Mx;
    }
    if (lane == 0) {
        float xk = own[row] * K_LOG2;
        pout[row] = NEG_EPS_LN2 * (m + __log2f(s) - xk) + EPS_NEG_LOGMU;
        prevmax[idx] = m;
        if (BUILD) cnt[idx] = ncand;
    }
}

// ---------- sparse Sinkhorn pass: LSE over candidate entries only ----------
// 384 blocks (128/pair); each block 32 rows (8 per wave). Dense fallback when
// cnt==0 or cnt>CAP — correctness never depends on the margin holding.
__global__ __launch_bounds__(256) void lse_sparse3_kernel(
    const _Float16* __restrict__ Sxy, const _Float16* __restrict__ STxy,
    const _Float16* __restrict__ Sxx, const _Float16* __restrict__ Syy,
    const float* __restrict__ x2, const float* __restrict__ y2,
    float* __restrict__ Pxy0, float* __restrict__ Pxy1,
    float* __restrict__ Pxx0, float* __restrict__ Pxx1,
    float* __restrict__ Pyy0, float* __restrict__ Pyy1,
    int odd,
    const unsigned int* __restrict__ cand, const int* __restrict__ cnt,
    float* __restrict__ prevmax) {
    __shared__ float gyk[N];
    int pair = blockIdx.x >> 7;     // 128 blocks per pair
    int pblk = blockIdx.x & 127;
    const _Float16* M;
    const float *own, *other, *pin;
    float* pout;
    if (pair == 0) {
        if (odd) { M = Sxy;  own = x2; other = y2; pin = Pxy0; pout = Pxy1; }
        else     { M = STxy; own = y2; other = x2; pin = Pxy1; pout = Pxy0; }
    } else if (pair == 1) {
        M = Sxx; own = x2; other = x2;
        if (odd) { pin = Pxx0; pout = Pxx1; } else { pin = Pxx1; pout = Pxx0; }
    } else {
        M = Syy; own = y2; other = y2;
        if (odd) { pin = Pyy0; pout = Pyy1; } else { pin = Pyy1; pout = Pyy0; }
    }

    {   // stage gyk
        const floatx4* pi4 = (const floatx4*)pin;
        const floatx4* so4 = (const floatx4*)other;
        floatx4* gy4 = (floatx4*)gyk;
        for (int tt = threadIdx.x; tt < N / 4; tt += 256) {
            floatx4 p = pi4[tt], o = so4[tt];
            floatx4 r;
#pragma unroll
            for (int k = 0; k < 4; k++) r[k] = (p[k] - o[k]) * K_LOG2;
            gy4[tt] = r;
        }
    }
    __syncthreads();

    int wave = threadIdx.x >> 6, lane = threadIdx.x & 63;
    int set = pair * 2 + (odd ? 0 : 1);

    for (int i = 0; i < 8; i++) {
        int row = pblk * 32 + wave * 8 + i;
        int idx = set * N + row;
        int c = cnt[idx];
        float m = -INFINITY, s = 0.f;
        if (c >= 1 && c <= CAP) {
            size_t cbase = (size_t)idx * CAP;
            for (int b = 0; b < c; b += 64) {
                int t = b + lane;
                if (t < c) {
                    unsigned int pk = cand[cbase + t];
                    _Float16 h = __builtin_bit_cast(_Float16, (unsigned short)(pk & 0xffffu));
                    float u = fmaf((float)h, TWO_K, gyk[pk >> 16]);
                    float Mx = fmaxf(m, u);
                    s = s * exp2f(m - Mx) + exp2f(u - Mx);
                    m = Mx;
                }
            }
        } else {
            const halfx8* rowp = (const halfx8*)(M + (size_t)row * N);
            for (int ch = lane; ch < N / 8; ch += 64) {
                halfx8 sv = rowp[ch];
                int j0 = ch * 8;
                float u[8];
#pragma unroll
                for (int k = 0; k < 8; k++)
                    u[k] = fmaf((float)sv[k], TWO_K, gyk[j0 + k]);
                float mloc = fmaxf(fmaxf(fmaxf(u[0], u[1]), fmaxf(u[2], u[3])),
                                   fmaxf(fmaxf(u[4], u[5]), fmaxf(u[6], u[7])));
                float M2 = fmaxf(m, mloc);
                float acc = 0.f;
#pragma unroll
                for (int k = 0; k < 8; k++) acc += exp2f(u[k] - M2);
                s = s * exp2f(m - M2) + acc;
                m = M2;
            }
        }
        // wave merge with -inf guards (empty lanes)
        for (int off = 32; off > 0; off >>= 1) {
            float m2 = __shfl_down(m, off), s2 = __shfl_down(s, off);
            float Mx = fmaxf(m, m2);
            float a1 = (m  == -INFINITY) ? 0.f : s  * exp2f(m  - Mx);
            float a2 = (m2 == -INFINITY) ? 0.f : s2 * exp2f(m2 - Mx);
            m = Mx; s = a1 + a2;
        }
        if (lane == 0) {
            float xk = own[row] * K_LOG2;
            pout[row] = NEG_EPS_LN2 * (m + __log2f(s) - xk) + EPS_NEG_LOGMU;
            prevmax[idx] = m;
        }
    }
}

// ---------- final: relu( mean(f_xy+g_xy) - 0.5*mean(f_xx+g_xx) - 0.5*mean(f_yy+g_yy) )
__global__ void finalize_kernel(const float* __restrict__ fxy, const float* __restrict__ gxy,
                                const float* __restrict__ fxx, const float* __restrict__ gxx,
                                const float* __restrict__ fyy, const float* __restrict__ gyy,
                                float* __restrict__ out) {
    __shared__ float sb[256];
    float s = 0.f;
    for (int t = threadIdx.x; t < N; t += 256)
        s += (fxy[t] + gxy[t]) - 0.5f * (fxx[t] + gxx[t]) - 0.5f * (fyy[t] + gyy[t]);
    sb[threadIdx.x] = s;
    __syncthreads();
    for (int off = 128; off > 0; off >>= 1) {
        if (threadIdx.x < off) sb[threadIdx.x] += sb[threadIdx.x + off];
        __syncthreads();
    }
    if (threadIdx.x == 0) {
        float v = sb[0] * (1.0f / 4096.0f);
        out[0] = v > 0.f ? v : 0.f;
    }
}

extern "C" void kernel_launch(void* const* d_in, const int* in_sizes, int n_in,
                              void* d_out, int out_size, void* d_ws, size_t ws_size,
                              hipStream_t stream) {
    const float* x = (const float*)d_in[0];
    const float* y = (const float*)d_in[1];

    const size_t SZ_S = (size_t)N * N * sizeof(_Float16);   // 32 MiB
    const size_t SZ_B = (size_t)N * D * sizeof(__bf16);     // 4 MiB
    const size_t SZ_CAND = (size_t)6 * N * CAP * sizeof(unsigned int);  // 48 MiB

    char* w = (char*)d_ws;
    _Float16* Sxy  = (_Float16*)w; w += SZ_S;
    _Float16* STxy = (_Float16*)w; w += SZ_S;
    _Float16* Sxx  = (_Float16*)w; w += SZ_S;
    _Float16* Syy  = (_Float16*)w; w += SZ_S;
    __bf16* xb = (__bf16*)w;       w += SZ_B;
    __bf16* yb = (__bf16*)w;       w += SZ_B;
    unsigned int* cand = (unsigned int*)w; w += SZ_CAND;
    int* cnt = (int*)w;            w += (size_t)6 * N * sizeof(int);
    float* prevmax = (float*)w;    w += (size_t)6 * N * sizeof(float);
    float* x2 = (float*)w;         w += N * sizeof(float);
    float* y2 = (float*)w;         w += N * sizeof(float);
    float* P[6];
    for (int i = 0; i < 6; i++) { P[i] = (float*)w; w += N * sizeof(float); }

    const size_t need = (size_t)(w - (char*)d_ws);
    const bool sparse_ok = (ws_size >= need);

    cvt_bf16_kernel<<<(N * D + 255) / 256, 256, 0, stream>>>(x, xb, N * D);
    cvt_bf16_kernel<<<(N * D + 255) / 256, 256, 0, stream>>>(y, yb, N * D);
    sqnorm_kernel<<<N, 64, 0, stream>>>(x, x2);
    sqnorm_kernel<<<N, 64, 0, stream>>>(y, y2);

    gemm128_kernel<<<dim3(32, 32), 256, 0, stream>>>(xb, yb, Sxy, STxy, 0);
    gemm128_kernel<<<dim3(32, 32), 256, 0, stream>>>(xb, xb, Sxx, Sxx, 1);
    gemm128_kernel<<<dim3(32, 32), 256, 0, stream>>>(yb, yb, Syy, Syy, 1);

    hipMemsetAsync(P[0], 0, N * sizeof(float), stream);  // g0_xy
    hipMemsetAsync(P[2], 0, N * sizeof(float), stream);  // g0_xx
    hipMemsetAsync(P[4], 0, N * sizeof(float), stream);  // g0_yy

    for (int p = 1; p <= SINK_PASSES; p++) {
        int odd = p & 1;
        bool full, build;
        if (!sparse_ok) { full = true; build = false; }
        else if (p <= 8) { full = true; build = false; }
        else { int q = (p - 9) % 16; build = (q < 2); full = build; }

        if (full) {
            if (build)
                lse_full3_kernel<1><<<3 * (N / 4), 256, 0, stream>>>(
                    Sxy, STxy, Sxx, Syy, x2, y2,
                    P[0], P[1], P[2], P[3], P[4], P[5], odd, cand, cnt, prevmax);
            else
                lse_full3_kernel<0><<<3 * (N / 4), 256, 0, stream>>>(
                    Sxy, STxy, Sxx, Syy, x2, y2,
                    P[0], P[1], P[2], P[3], P[4], P[5], odd, cand, cnt, prevmax);
        } else {
            lse_sparse3_kernel<<<3 * 128, 256, 0, stream>>>(
                Sxy, STxy, Sxx, Syy, x2, y2,
                P[0], P[1], P[2], P[3], P[4], P[5], odd, cand, cnt, prevmax);
        }
    }
    finalize_kernel<<<1, 256, 0, stream>>>(P[1], P[0], P[3], P[2], P[5], P[4],
                                           (float*)d_out);
}

// Round 7
// 1216.988 us; speedup vs baseline: 11.8217x; 1.3837x over previous
//
#include <hip/hip_runtime.h>
#include <hip/hip_bf16.h>
#include <math.h>

// Problem constants (fixed by reference: x,y are (4096, 512) fp32)
#define N 4096
#define D 512
#define SINK_PASSES 100           // 50 iterations x (f-update, g-update)

// log-domain constants (base-2 internally; v_exp_f32/v_log_f32 are base-2)
#define K_LOG2 14.426950408889634f          // (1/eps) * log2(e), eps = 0.1
#define TWO_K  28.853900817779268f          // 2 * K_LOG2
#define NEG_EPS_LN2 (-0.06931471805599453f) // -eps * ln(2)
#define EPS_NEG_LOGMU 0.8317766166719343f   // -eps * log_mu = eps * log(4096)

// Sparse-candidate machinery: entries with u < rowmax - MARGIN (log2 units)
// contribute < 2^-MARGIN each; MARGIN=600 covers potential drift between the
// two build events (p=9/10 and p=49/50) with >10x headroom (see R5/R6 absmax).
#define CAP 512
#define MARGIN 600.0f

typedef __bf16   bf16x8 __attribute__((ext_vector_type(8)));
typedef _Float16 halfx8 __attribute__((ext_vector_type(8)));
typedef float    floatx4 __attribute__((ext_vector_type(4)));
typedef unsigned short ushortx8v __attribute__((ext_vector_type(8)));

// ---------- convert fp32 -> bf16 (GEMM inputs) ----------
__global__ void cvt_bf16_kernel(const float* __restrict__ in, __bf16* __restrict__ out, int count) {
    int idx = blockIdx.x * blockDim.x + threadIdx.x;
    if (idx < count) out[idx] = (__bf16)in[idx];
}

// ---------- row squared norms (fp32 inputs, exact) ----------
__global__ void sqnorm_kernel(const float* __restrict__ in, float* __restrict__ out) {
    int row = blockIdx.x;
    const float* p = in + (size_t)row * D;
    float s = 0.f;
    for (int k = threadIdx.x; k < D; k += 64) { float v = p[k]; s += v * v; }
    for (int off = 32; off > 0; off >>= 1) s += __shfl_down(s, off);
    if (threadIdx.x == 0) out[row] = s;
}

// ---------- 128x128-tile GEMM: out = A @ B^T (fp16), writes tile + transposed tile ----------
// (round-4 proven; sym=1 computes upper-triangle blocks + mirror writes)
__global__ __launch_bounds__(256) void gemm128_kernel(
    const __bf16* __restrict__ A, const __bf16* __restrict__ Bm,
    _Float16* __restrict__ out1, _Float16* __restrict__ out2, int sym) {
    if (sym && blockIdx.x > blockIdx.y) return;
    __shared__ char smem[34816];
    __bf16* ldsA = (__bf16*)smem;           // [128][64] swizzled
    __bf16* ldsB = ldsA + 128 * 64;

    int t = threadIdx.x;
    int w = t >> 6, lane = t & 63;
    int m = lane & 15, q = lane >> 4;
    int wr = w & 1, wc = w >> 1;
    int m0 = blockIdx.x * 128, n0 = blockIdx.y * 128;

    int srow = t >> 1, shalf = t & 1;
    const bf16x8* gA = (const bf16x8*)(A  + (size_t)(m0 + srow) * D + shalf * 32);
    const bf16x8* gB = (const bf16x8*)(Bm + (size_t)(n0 + srow) * D + shalf * 32);

    floatx4 acc[4][4];
#pragma unroll
    for (int i = 0; i < 4; i++)
#pragma unroll
        for (int j = 0; j < 4; j++) acc[i][j] = (floatx4){0.f, 0.f, 0.f, 0.f};

    for (int slab = 0; slab < 8; slab++) {
        bf16x8 va[4], vb[4];
#pragma unroll
        for (int i = 0; i < 4; i++) {
            va[i] = gA[slab * 8 + i];
            vb[i] = gB[slab * 8 + i];
        }
        __syncthreads();
#pragma unroll
        for (int i = 0; i < 4; i++) {
            int cp = (shalf * 4 + i) ^ (srow & 7);
            *(bf16x8*)(ldsA + srow * 64 + cp * 8) = va[i];
            *(bf16x8*)(ldsB + srow * 64 + cp * 8) = vb[i];
        }
        __syncthreads();
#pragma unroll
        for (int kk = 0; kk < 2; kk++) {
            bf16x8 af[4], bfr[4];
#pragma unroll
            for (int mt = 0; mt < 4; mt++) {
                int cp = (kk * 4 + q) ^ (m & 7);
                af[mt]  = *(const bf16x8*)(ldsA + (wr * 64 + mt * 16 + m) * 64 + cp * 8);
                bfr[mt] = *(const bf16x8*)(ldsB + (wc * 64 + mt * 16 + m) * 64 + cp * 8);
            }
#pragma unroll
            for (int mt = 0; mt < 4; mt++)
#pragma unroll
                for (int nt = 0; nt < 4; nt++)
                    acc[mt][nt] = __builtin_amdgcn_mfma_f32_16x16x32_bf16(
                        af[mt], bfr[nt], acc[mt][nt], 0, 0, 0);
        }
    }

    __syncthreads();
    _Float16* et = (_Float16*)smem + w * (64 * 66);
#pragma unroll
    for (int mt = 0; mt < 4; mt++)
#pragma unroll
        for (int nt = 0; nt < 4; nt++)
#pragma unroll
            for (int r = 0; r < 4; r++)
                et[(mt * 16 + q * 4 + r) * 66 + nt * 16 + m] = (_Float16)acc[mt][nt][r];

    int l3 = lane >> 3, c8 = lane & 7;
#pragma unroll
    for (int rr = 0; rr < 8; rr++) {
        int rl = rr * 8 + l3;
        halfx8 v = *(const halfx8*)(et + rl * 66 + c8 * 8);
        *(halfx8*)(out1 + (size_t)(m0 + wr * 64 + rl) * N + n0 + wc * 64 + c8 * 8) = v;
    }
#pragma unroll
    for (int rr = 0; rr < 8; rr++) {
        int rT = rr * 8 + l3;
        halfx8 v;
#pragma unroll
        for (int k = 0; k < 8; k++) v[k] = et[(c8 * 8 + k) * 66 + rT];
        *(halfx8*)(out2 + (size_t)(n0 + wc * 64 + rT) * N + m0 + wr * 64 + c8 * 8) = v;
    }
}

// ---------- full Sinkhorn pass (3 pairs, 1 row/wave, 3072 blocks) ----------
// gyk staged TRANSPOSED in LDS: gykT[k][j>>3] so the read gykT[k*512+chunk]
// is lane-consecutive -> conflict-free (the old layout was 16-way conflicted).
// BUILD=1: collect candidates u >= prevmax - MARGIN via ballot compaction,
// with a chunk-level ballot skip (hits are rare). Every variant stores this
// pass's row max into prevmax[].
template<int BUILD>
__global__ __launch_bounds__(256) void lse_full3_kernel(
    const _Float16* __restrict__ Sxy, const _Float16* __restrict__ STxy,
    const _Float16* __restrict__ Sxx, const _Float16* __restrict__ Syy,
    const float* __restrict__ x2, const float* __restrict__ y2,
    float* __restrict__ Pxy0, float* __restrict__ Pxy1,
    float* __restrict__ Pxx0, float* __restrict__ Pxx1,
    float* __restrict__ Pyy0, float* __restrict__ Pyy1,
    int odd,
    unsigned int* __restrict__ cand, int* __restrict__ cnt,
    float* __restrict__ prevmax) {
    __shared__ float gykT[8 * 512];
    int pair = blockIdx.x >> 10;
    int blk = blockIdx.x & 1023;
    const _Float16* M;
    const float *own, *other, *pin;
    float* pout;
    if (pair == 0) {
        if (odd) { M = Sxy;  own = x2; other = y2; pin = Pxy0; pout = Pxy1; }
        else     { M = STxy; own = y2; other = x2; pin = Pxy1; pout = Pxy0; }
    } else if (pair == 1) {
        M = Sxx; own = x2; other = x2;
        if (odd) { pin = Pxx0; pout = Pxx1; } else { pin = Pxx1; pout = Pxx0; }
    } else {
        M = Syy; own = y2; other = y2;
        if (odd) { pin = Pyy0; pout = Pyy1; } else { pin = Pyy1; pout = Pyy0; }
    }

    int wave = threadIdx.x >> 6, lane = threadIdx.x & 63;

    {   // stage gykT[(j&7)*512 + (j>>3)] = (pin[j] - other[j]) * K
        const floatx4* pi4 = (const floatx4*)pin;
        const floatx4* so4 = (const floatx4*)other;
        for (int tt = threadIdx.x; tt < N / 4; tt += 256) {
            floatx4 p = pi4[tt], o = so4[tt];
            int j = tt * 4;
#pragma unroll
            for (int k2 = 0; k2 < 4; k2++) {
                int jj = j + k2;
                gykT[(jj & 7) * 512 + (jj >> 3)] = (p[k2] - o[k2]) * K_LOG2;
            }
        }
    }
    __syncthreads();

    int row = blk * 4 + wave;
    int set = pair * 2 + (odd ? 0 : 1);
    int idx = set * N + row;
    float thr = 0.f;
    size_t cbase = 0;
    int ncand = 0;
    unsigned long long lt_mask = (1ull << lane) - 1ull;
    if (BUILD) { thr = prevmax[idx] - MARGIN; cbase = (size_t)idx * CAP; }

    const halfx8* srow = (const halfx8*)(M + (size_t)row * N);
    float m = -INFINITY, s = 0.f;
#pragma unroll
    for (int c = 0; c < 8; c++) {
        int chunk = c * 64 + lane;
        halfx8 sv = srow[chunk];
        int j0 = chunk * 8;
        float u[8];
#pragma unroll
        for (int k = 0; k < 8; k++)
            u[k] = fmaf((float)sv[k], TWO_K, gykT[k * 512 + chunk]);
        float mloc = fmaxf(fmaxf(fmaxf(u[0], u[1]), fmaxf(u[2], u[3])),
                           fmaxf(fmaxf(u[4], u[5]), fmaxf(u[6], u[7])));
        if (BUILD) {
            // chunk-level skip: only run the serialized per-k ballots if some
            // lane in the wave has a hit in this chunk (hits are rare).
            if (__ballot(mloc >= thr)) {
                ushortx8v sb = __builtin_bit_cast(ushortx8v, sv);
#pragma unroll
                for (int k = 0; k < 8; k++) {
                    bool hit = (u[k] >= thr);
                    unsigned long long mask = __ballot(hit);
                    if (hit) {
                        int slot = ncand + __popcll(mask & lt_mask);
                        if (slot < CAP)
                            cand[cbase + slot] = ((unsigned int)(j0 + k) << 16) | (unsigned int)sb[k];
                    }
                    ncand += (int)__popcll(mask);
                }
            }
        }
        float M2 = fmaxf(m, mloc);
        float acc = 0.f;
#pragma unroll
        for (int k = 0; k < 8; k++) acc += exp2f(u[k] - M2);
        s = s * exp2f(m - M2) + acc;
        m = M2;
    }
    for (int off = 32; off > 0; off >>= 1) {
        float m2 = __shfl_down(m, off), s2 = __shfl_down(s, off);
        float Mx = fmaxf(m, m2);
        s = s * exp2f(m - Mx) + s2 * exp2f(m2 - Mx);
        m = Mx;
    }
    if (lane == 0) {
        float xk = own[row] * K_LOG2;
        pout[row] = NEG_EPS_LN2 * (m + __log2f(s) - xk) + EPS_NEG_LOGMU;
        prevmax[idx] = m;
        if (BUILD) cnt[idx] = ncand;
    }
}

// ---------- sparse Sinkhorn pass v2: no LDS, no barrier ----------
// 768 blocks x 4 waves; each wave owns 4 rows. Per candidate: gather
// pin[j], other[j] directly (16KB arrays, L1-hot). Batched u[8] in registers,
// wave-wide shfl_xor max then sum (no serialized streaming merge).
// Dense fallback (direct global reads) when cnt==0 or cnt>CAP.
__global__ __launch_bounds__(256) void lse_sparse3_kernel(
    const _Float16* __restrict__ Sxy, const _Float16* __restrict__ STxy,
    const _Float16* __restrict__ Sxx, const _Float16* __restrict__ Syy,
    const float* __restrict__ x2, const float* __restrict__ y2,
    float* __restrict__ Pxy0, float* __restrict__ Pxy1,
    float* __restrict__ Pxx0, float* __restrict__ Pxx1,
    float* __restrict__ Pyy0, float* __restrict__ Pyy1,
    int odd,
    const unsigned int* __restrict__ cand, const int* __restrict__ cnt,
    float* __restrict__ prevmax) {
    int wave = threadIdx.x >> 6, lane = threadIdx.x & 63;
    int gwave = blockIdx.x * 4 + wave;        // 0..3071
    int pair = gwave >> 10;                   // 1024 waves per pair
    int pwave = gwave & 1023;                 // rows pwave*4 .. +3
    const _Float16* M;
    const float *own, *other, *pin;
    float* pout;
    if (pair == 0) {
        if (odd) { M = Sxy;  own = x2; other = y2; pin = Pxy0; pout = Pxy1; }
        else     { M = STxy; own = y2; other = x2; pin = Pxy1; pout = Pxy0; }
    } else if (pair == 1) {
        M = Sxx; own = x2; other = x2;
        if (odd) { pin = Pxx0; pout = Pxx1; } else { pin = Pxx1; pout = Pxx0; }
    } else {
        M = Syy; own = y2; other = y2;
        if (odd) { pin = Pyy0; pout = Pyy1; } else { pin = Pyy1; pout = Pyy0; }
    }
    int set = pair * 2 + (odd ? 0 : 1);

    for (int i = 0; i < 4; i++) {
        int row = pwave * 4 + i;
        int idx = set * N + row;
        int c = cnt[idx];
        float m, s;
        if (c >= 1 && c <= CAP) {
            size_t cbase = (size_t)idx * CAP;
            int nb = (c + 63) >> 6;
            float uu[8];
            float lm = -INFINITY;
#pragma unroll 8
            for (int b = 0; b < 8; b++) {
                uu[b] = -INFINITY;
                if (b < nb) {
                    int t = b * 64 + lane;
                    if (t < c) {
                        unsigned int pk = cand[cbase + t];
                        int j = pk >> 16;
                        _Float16 h = __builtin_bit_cast(_Float16, (unsigned short)(pk & 0xffffu));
                        uu[b] = fmaf((float)h, TWO_K, (pin[j] - other[j]) * K_LOG2);
                    }
                    lm = fmaxf(lm, uu[b]);
                }
            }
            // wave-wide max (butterfly: all lanes get result)
            for (int off = 32; off > 0; off >>= 1)
                lm = fmaxf(lm, __shfl_xor(lm, off));
            float ls = 0.f;
#pragma unroll 8
            for (int b = 0; b < 8; b++)
                if (b < nb) ls += exp2f(uu[b] - lm);   // -inf -> 0
            for (int off = 32; off > 0; off >>= 1)
                ls += __shfl_xor(ls, off);
            m = lm; s = ls;
        } else {
            // dense fallback: direct global reads (rare)
            m = -INFINITY; s = 0.f;
            const halfx8* rowp = (const halfx8*)(M + (size_t)row * N);
            for (int ch = lane; ch < N / 8; ch += 64) {
                halfx8 sv = rowp[ch];
                int j0 = ch * 8;
                floatx4 p0 = *(const floatx4*)(pin + j0);
                floatx4 p1 = *(const floatx4*)(pin + j0 + 4);
                floatx4 o0 = *(const floatx4*)(other + j0);
                floatx4 o1 = *(const floatx4*)(other + j0 + 4);
                float u[8];
#pragma unroll
                for (int k = 0; k < 4; k++) {
                    u[k]     = fmaf((float)sv[k],     TWO_K, (p0[k] - o0[k]) * K_LOG2);
                    u[k + 4] = fmaf((float)sv[k + 4], TWO_K, (p1[k] - o1[k]) * K_LOG2);
                }
                float mloc = fmaxf(fmaxf(fmaxf(u[0], u[1]), fmaxf(u[2], u[3])),
                                   fmaxf(fmaxf(u[4], u[5]), fmaxf(u[6], u[7])));
                float M2 = fmaxf(m, mloc);
                float acc = 0.f;
#pragma unroll
                for (int k = 0; k < 8; k++) acc += exp2f(u[k] - M2);
                s = s * exp2f(m - M2) + acc;
                m = M2;
            }
            for (int off = 32; off > 0; off >>= 1) {
                float m2 = __shfl_xor(m, off), s2 = __shfl_xor(s, off);
                float Mx = fmaxf(m, m2);
                float a1 = (m  == -INFINITY) ? 0.f : s  * exp2f(m  - Mx);
                float a2 = (m2 == -INFINITY) ? 0.f : s2 * exp2f(m2 - Mx);
                m = Mx; s = a1 + a2;
            }
        }
        if (lane == 0) {
            float xk = own[row] * K_LOG2;
            pout[row] = NEG_EPS_LN2 * (m + __log2f(s) - xk) + EPS_NEG_LOGMU;
            prevmax[idx] = m;
        }
    }
}

// ---------- final: relu( mean(f_xy+g_xy) - 0.5*mean(f_xx+g_xx) - 0.5*mean(f_yy+g_yy) )
__global__ void finalize_kernel(const float* __restrict__ fxy, const float* __restrict__ gxy,
                                const float* __restrict__ fxx, const float* __restrict__ gxx,
                                const float* __restrict__ fyy, const float* __restrict__ gyy,
                                float* __restrict__ out) {
    __shared__ float sb[256];
    float s = 0.f;
    for (int t = threadIdx.x; t < N; t += 256)
        s += (fxy[t] + gxy[t]) - 0.5f * (fxx[t] + gxx[t]) - 0.5f * (fyy[t] + gyy[t]);
    sb[threadIdx.x] = s;
    __syncthreads();
    for (int off = 128; off > 0; off >>= 1) {
        if (threadIdx.x < off) sb[threadIdx.x] += sb[threadIdx.x + off];
        __syncthreads();
    }
    if (threadIdx.x == 0) {
        float v = sb[0] * (1.0f / 4096.0f);
        out[0] = v > 0.f ? v : 0.f;
    }
}

extern "C" void kernel_launch(void* const* d_in, const int* in_sizes, int n_in,
                              void* d_out, int out_size, void* d_ws, size_t ws_size,
                              hipStream_t stream) {
    const float* x = (const float*)d_in[0];
    const float* y = (const float*)d_in[1];

    const size_t SZ_S = (size_t)N * N * sizeof(_Float16);   // 32 MiB
    const size_t SZ_B = (size_t)N * D * sizeof(__bf16);     // 4 MiB
    const size_t SZ_CAND = (size_t)6 * N * CAP * sizeof(unsigned int);  // 48 MiB

    char* w = (char*)d_ws;
    _Float16* Sxy  = (_Float16*)w; w += SZ_S;
    _Float16* STxy = (_Float16*)w; w += SZ_S;
    _Float16* Sxx  = (_Float16*)w; w += SZ_S;
    _Float16* Syy  = (_Float16*)w; w += SZ_S;
    __bf16* xb = (__bf16*)w;       w += SZ_B;
    __bf16* yb = (__bf16*)w;       w += SZ_B;
    unsigned int* cand = (unsigned int*)w; w += SZ_CAND;
    int* cnt = (int*)w;            w += (size_t)6 * N * sizeof(int);
    float* prevmax = (float*)w;    w += (size_t)6 * N * sizeof(float);
    float* x2 = (float*)w;         w += N * sizeof(float);
    float* y2 = (float*)w;         w += N * sizeof(float);
    float* P[6];
    for (int i = 0; i < 6; i++) { P[i] = (float*)w; w += N * sizeof(float); }

    const size_t need = (size_t)(w - (char*)d_ws);
    const bool sparse_ok = (ws_size >= need);

    cvt_bf16_kernel<<<(N * D + 255) / 256, 256, 0, stream>>>(x, xb, N * D);
    cvt_bf16_kernel<<<(N * D + 255) / 256, 256, 0, stream>>>(y, yb, N * D);
    sqnorm_kernel<<<N, 64, 0, stream>>>(x, x2);
    sqnorm_kernel<<<N, 64, 0, stream>>>(y, y2);

    gemm128_kernel<<<dim3(32, 32), 256, 0, stream>>>(xb, yb, Sxy, STxy, 0);
    gemm128_kernel<<<dim3(32, 32), 256, 0, stream>>>(xb, xb, Sxx, Sxx, 1);
    gemm128_kernel<<<dim3(32, 32), 256, 0, stream>>>(yb, yb, Syy, Syy, 1);

    hipMemsetAsync(P[0], 0, N * sizeof(float), stream);  // g0_xy
    hipMemsetAsync(P[2], 0, N * sizeof(float), stream);  // g0_xx
    hipMemsetAsync(P[4], 0, N * sizeof(float), stream);  // g0_yy

    for (int p = 1; p <= SINK_PASSES; p++) {
        int odd = p & 1;
        bool build = sparse_ok && (p == 9 || p == 10 || p == 49 || p == 50);
        bool full  = !sparse_ok || p <= 8 || build;

        if (full) {
            if (build)
                lse_full3_kernel<1><<<3 * (N / 4), 256, 0, stream>>>(
                    Sxy, STxy, Sxx, Syy, x2, y2,
                    P[0], P[1], P[2], P[3], P[4], P[5], odd, cand, cnt, prevmax);
            else
                lse_full3_kernel<0><<<3 * (N / 4), 256, 0, stream>>>(
                    Sxy, STxy, Sxx, Syy, x2, y2,
                    P[0], P[1], P[2], P[3], P[4], P[5], odd, cand, cnt, prevmax);
        } else {
            lse_sparse3_kernel<<<768, 256, 0, stream>>>(
                Sxy, STxy, Sxx, Syy, x2, y2,
                P[0], P[1], P[2], P[3], P[4], P[5], odd, cand, cnt, prevmax);
        }
    }
    finalize_kernel<<<1, 256, 0, stream>>>(P[1], P[0], P[3], P[2], P[5], P[4],
                                           (float*)d_out);
}